// Round 9
// baseline (260.934 us; speedup 1.0000x reference)
//
#include <hip/hip_runtime.h>
#include <hip/hip_bf16.h>
#include <stdint.h>

#define HW_ 4096

typedef short bf16x8 __attribute__((ext_vector_type(8)));
typedef short short4v __attribute__((ext_vector_type(4)));
typedef short short8v __attribute__((ext_vector_type(8)));
typedef float f32x4 __attribute__((ext_vector_type(4)));
typedef float f32x16 __attribute__((ext_vector_type(16)));
typedef uint32_t u32x4 __attribute__((ext_vector_type(4)));

__device__ inline unsigned short f2bf(float x) {
  uint32_t u = __builtin_bit_cast(uint32_t, x);
  uint32_t r = ((u >> 16) & 1u) + 0x7fffu;
  return (unsigned short)((u + r) >> 16);
}
__device__ inline uint32_t cvt_pk_bf16(float lo, float hi) {
  uint32_t r;
  asm("v_cvt_pk_bf16_f32 %0, %1, %2" : "=v"(r) : "v"(lo), "v"(hi));
  return r;
}
__device__ inline float bf_lo(uint32_t u) { return __builtin_bit_cast(float, u << 16); }
__device__ inline float bf_hi(uint32_t u) { return __builtin_bit_cast(float, u & 0xffff0000u); }
__device__ inline void gld_lds16(const unsigned short* g, unsigned short* l) {
  __builtin_amdgcn_global_load_lds((const __attribute__((address_space(1))) void*)g,
                                   (__attribute__((address_space(3))) void*)l, 16, 0, 0);
}

// fused waitcnt+barrier: single asm block with memory clobber so NO memory op
// (ds_read of the compute, gld_lds16 of the stage) can cross the barrier.
// Raw __builtin_amdgcn_s_barrier() alone is NOT an IR-level memory fence.
#define WAIT_BARRIER(VMSTR)                                                  \
  asm volatile("s_waitcnt " VMSTR "\n\ts_barrier" ::: "memory");             \
  __builtin_amdgcn_sched_barrier(0);

// ---------------- xconv: fp32 [b][c][p] -> bf16 cgroup layout [(b*32+cg)][p][e] ----------------
__global__ __launch_bounds__(256) void xconv_kernel(
    const float* __restrict__ X, unsigned short* __restrict__ Y) {
  const int i = blockIdx.x * 256 + threadIdx.x;
  const int p = i & 4095;
  const int cg = (i >> 12) & 31;
  const int b = i >> 17;
  const float* src = X + ((size_t)b * 256 + cg * 8) * HW_ + p;
  float v[8];
#pragma unroll
  for (int e = 0; e < 8; ++e) v[e] = src[(size_t)e * HW_];
  uint4 o;
  o.x = cvt_pk_bf16(v[0], v[1]);
  o.y = cvt_pk_bf16(v[2], v[3]);
  o.z = cvt_pk_bf16(v[4], v[5]);
  o.w = cvt_pk_bf16(v[6], v[7]);
  *(uint4*)&Y[((size_t)(b * 32 + cg) * HW_ + p) * 8] = o;
}

// ---------------- prep: 4x wconv (fp32 W[o][c] -> bf16 [cg][o][e]) + wtrans ----------------
__global__ __launch_bounds__(256) void prep_kernel(
    const float* __restrict__ Wq, const float* __restrict__ Wk,
    const float* __restrict__ Wv, const float* __restrict__ Wp,
    const float* __restrict__ fw,
    unsigned short* __restrict__ WqB, unsigned short* __restrict__ WkB,
    unsigned short* __restrict__ WvB, unsigned short* __restrict__ WpB,
    unsigned short* __restrict__ wt) {
  const int blk = blockIdx.x;
  if (blk < 128) {
    const int which = blk >> 5;
    const float* W = which == 0 ? Wq : which == 1 ? Wk : which == 2 ? Wv : Wp;
    unsigned short* Y = which == 0 ? WqB : which == 1 ? WkB : which == 2 ? WvB : WpB;
    const int i = (blk & 31) * 256 + threadIdx.x;  // 8192
    const int o = i & 255;
    const int cg = i >> 8;
    float4 a = *(const float4*)&W[(size_t)o * 256 + cg * 8];
    float4 bq = *(const float4*)&W[(size_t)o * 256 + cg * 8 + 4];
    uint4 ov;
    ov.x = cvt_pk_bf16(a.x, a.y);
    ov.y = cvt_pk_bf16(a.z, a.w);
    ov.z = cvt_pk_bf16(bq.x, bq.y);
    ov.w = cvt_pk_bf16(bq.z, bq.w);
    *(uint4*)&Y[((size_t)cg * 256 + o) * 8] = ov;
  } else {
    const size_t i = (size_t)(blk - 128) * 256 + threadIdx.x;  // 256*512
    const int oc = (int)(i >> 9);
    const int ic = (int)(i & 511);
    const float* src = fw + i * 9;
#pragma unroll
    for (int tap = 0; tap < 9; ++tap)
      wt[((size_t)tap * 256 + oc) * 512 + ic] = f2bf(src[tap]);
  }
}

// ---------------- MFMA GEMM, counted-vmcnt 4-buf pipeline ----------------
// Xbf: [(b*32+cg)][p][e], Wbf: [cg][o][e]. Block 64o x 128p, 4 waves.
// mode 1: bf16 [b*4+oy][p][dd]*oscale; 2: bf16 [b][o][p]; 3: bf16 cgroup.
#define GSTAGE(KS, BUF)                                                       \
  gld_lds16(Xb + ((size_t)((KS) * 2 + (t >> 7)) * HW_ + p0 + (t & 127)) * 8,  \
            &X_l[BUF][0][0][0] + (size_t)t * 8);
#define GCOMP(KS)                                                             \
  {                                                                           \
    bf16x8 af = *(const bf16x8*)&W_l[(KS) * 2 + g32][wo * 32 + n][0];         \
    bf16x8 b0 = *(const bf16x8*)&X_l[(KS) & 3][g32][wp * 64 + n][0];          \
    bf16x8 b1 = *(const bf16x8*)&X_l[(KS) & 3][g32][wp * 64 + 32 + n][0];     \
    acc[0] = __builtin_amdgcn_mfma_f32_32x32x16_bf16(af, b0, acc[0], 0, 0, 0);\
    acc[1] = __builtin_amdgcn_mfma_f32_32x32x16_bf16(af, b1, acc[1], 0, 0, 0);\
  }

__global__ __launch_bounds__(256) void gemm_mfma_kernel(
    const unsigned short* __restrict__ Xbf, const unsigned short* __restrict__ Wbf,
    void* __restrict__ Yv, int mode, float oscale) {
  __shared__ unsigned short W_l[32][64][8];     // 32KB, staged once
  __shared__ unsigned short X_l[4][2][128][8];  // 16KB ring
  const int t = threadIdx.x;
  const int w = t >> 6;
  const int l = t & 63;
  const int n = l & 31;
  const int g32 = l >> 5;
  const int p0 = blockIdx.x * 128;
  const int o0 = blockIdx.y * 64;
  const int b = blockIdx.z;
  const int wo = w >> 1, wp = w & 1;
  const unsigned short* Xb = Xbf + (size_t)b * 32 * HW_ * 8;

#pragma unroll
  for (int j = 0; j < 8; ++j) {
    const int i = j * 256 + t;
    gld_lds16(Wbf + ((size_t)(i >> 6) * 256 + o0 + (i & 63)) * 8,
              &W_l[0][0][0] + (size_t)i * 8);
  }
  GSTAGE(0, 0)
  GSTAGE(1, 1)
  GSTAGE(2, 2)

  f32x16 acc[2] = {};
  for (int ks = 0; ks < 13; ++ks) {
    WAIT_BARRIER("vmcnt(2)")
    GSTAGE(ks + 3, (ks + 3) & 3)
    GCOMP(ks)
  }
  WAIT_BARRIER("vmcnt(2)")
  GCOMP(13)
  WAIT_BARRIER("vmcnt(1)")
  GCOMP(14)
  WAIT_BARRIER("vmcnt(0)")
  GCOMP(15)

  if (mode == 1) {
    unsigned short* Y = (unsigned short*)Yv;
    const size_t bh = (size_t)b * 4 + blockIdx.y;
#pragma unroll
    for (int pf = 0; pf < 2; ++pf) {
      const int p = p0 + wp * 64 + pf * 32 + n;
      unsigned short* dst = Y + (bh * HW_ + p) * 64 + wo * 32 + 4 * g32;
#pragma unroll
      for (int q = 0; q < 4; ++q) {
        uint2 uu;
        uu.x = cvt_pk_bf16(acc[pf][q * 4 + 0] * oscale, acc[pf][q * 4 + 1] * oscale);
        uu.y = cvt_pk_bf16(acc[pf][q * 4 + 2] * oscale, acc[pf][q * 4 + 3] * oscale);
        *(uint2*)&dst[8 * q] = uu;
      }
    }
  } else if (mode == 2) {
    unsigned short* Y = (unsigned short*)Yv;
#pragma unroll
    for (int pf = 0; pf < 2; ++pf) {
      const int p = p0 + wp * 64 + pf * 32 + n;
#pragma unroll
      for (int r = 0; r < 16; ++r) {
        const int m = (r & 3) + 8 * (r >> 2) + 4 * g32;
        Y[((size_t)b * 256 + o0 + wo * 32 + m) * HW_ + p] = f2bf(acc[pf][r]);
      }
    }
  } else {  // mode 3: bf16 cgroup [(b*32+cg)][p][e]
    unsigned short* Y = (unsigned short*)Yv;
    const int cgb = (o0 + wo * 32) >> 3;
#pragma unroll
    for (int pf = 0; pf < 2; ++pf) {
      const int p = p0 + wp * 64 + pf * 32 + n;
#pragma unroll
      for (int q = 0; q < 4; ++q) {
        uint2 uu;
        uu.x = cvt_pk_bf16(acc[pf][q * 4 + 0], acc[pf][q * 4 + 1]);
        uu.y = cvt_pk_bf16(acc[pf][q * 4 + 2], acc[pf][q * 4 + 3]);
        *(uint2*)&Y[((size_t)(b * 32 + cgb + q) * HW_ + p) * 8 + 4 * g32] = uu;
      }
    }
  }
}

// ---------------- MFMA flash attention: 32x32x16, 4-buf counted-vmcnt ----------------
// Swapped QK^T: accS^T[j][q], lane (n,h) owns q=q0+n, j=(r&3)+8(r>>2)+4h (+32 for aS1).
// PV k-permutation: slot (h,e) of MFMA #ks pairs P[q][j] with V[j][dd] for
// j = 16ks + 8*(e>=4) + 4h + (e&3); B-frag is then exactly ex[8ks..8ks+7] in order,
// A-frag two short4v reads from chunks 2ks, 2ks+1 at offset 4h.
#define ATTN_STAGE(SB)                                                       \
  {                                                                          \
    gld_lds16(gKp, kst + (SB) * 4096);                                       \
    gld_lds16(gKp + 8 * 64, kst + (SB) * 4096 + 512);                        \
    gld_lds16(gVp, vst + (SB) * 4096);                                       \
    gld_lds16(gVp + (size_t)8 * HW_, vst + (SB) * 4096 + 512);               \
    gKp += 4096;                                                             \
    gVp += 64;                                                               \
  }

#define ATTN_COMPUTE(BUF)                                                    \
  {                                                                          \
    f32x16 aS0 = zero16, aS1 = zero16;                                       \
    _Pragma("unroll") for (int s = 0; s < 4; ++s) {                          \
      bf16x8 kf0 = *(const bf16x8*)&k_l[(BUF) * 4096 + rowKA + kox[s]];      \
      bf16x8 kf1 = *(const bf16x8*)&k_l[(BUF) * 4096 + rowKB + kox[s]];      \
      aS0 = __builtin_amdgcn_mfma_f32_32x32x16_bf16(kf0, qf[s], aS0, 0, 0, 0); \
      aS1 = __builtin_amdgcn_mfma_f32_32x32x16_bf16(kf1, qf[s], aS1, 0, 0, 0); \
    }                                                                        \
    float ex0[16], ex1[16];                                                  \
    float rs = 0.f;                                                          \
    _Pragma("unroll") for (int r = 0; r < 16; ++r) {                         \
      ex0[r] = __builtin_amdgcn_exp2f(aS0[r]);                               \
      ex1[r] = __builtin_amdgcn_exp2f(aS1[r]);                               \
      rs += ex0[r] + ex1[r];                                                 \
    }                                                                        \
    l_r += rs;                                                               \
    union { u32x4 u4; bf16x8 v8; } pA, pB, pC, pD;                           \
    pA.u4 = (u32x4){cvt_pk_bf16(ex0[0], ex0[1]), cvt_pk_bf16(ex0[2], ex0[3]),    \
                    cvt_pk_bf16(ex0[4], ex0[5]), cvt_pk_bf16(ex0[6], ex0[7])};   \
    pB.u4 = (u32x4){cvt_pk_bf16(ex0[8], ex0[9]), cvt_pk_bf16(ex0[10], ex0[11]),  \
                    cvt_pk_bf16(ex0[12], ex0[13]), cvt_pk_bf16(ex0[14], ex0[15])};\
    pC.u4 = (u32x4){cvt_pk_bf16(ex1[0], ex1[1]), cvt_pk_bf16(ex1[2], ex1[3]),    \
                    cvt_pk_bf16(ex1[4], ex1[5]), cvt_pk_bf16(ex1[6], ex1[7])};   \
    pD.u4 = (u32x4){cvt_pk_bf16(ex1[8], ex1[9]), cvt_pk_bf16(ex1[10], ex1[11]),  \
                    cvt_pk_bf16(ex1[12], ex1[13]), cvt_pk_bf16(ex1[14], ex1[15])};\
    _Pragma("unroll") for (int dh = 0; dh < 2; ++dh) {                       \
      const int rw = (BUF) * 4096 + (dh * 32 + n) * 64;                      \
      union { short4v h2[2]; bf16x8 v8; } v0, v1, v2, v3;                    \
      v0.h2[0] = *(const short4v*)&v_l[rw + voA0];                           \
      v0.h2[1] = *(const short4v*)&v_l[rw + voA1];                           \
      v1.h2[0] = *(const short4v*)&v_l[rw + voB0];                           \
      v1.h2[1] = *(const short4v*)&v_l[rw + voB1];                           \
      v2.h2[0] = *(const short4v*)&v_l[rw + voC0];                           \
      v2.h2[1] = *(const short4v*)&v_l[rw + voC1];                           \
      v3.h2[0] = *(const short4v*)&v_l[rw + voD0];                           \
      v3.h2[1] = *(const short4v*)&v_l[rw + voD1];                           \
      f32x16 ac = accO[dh];                                                  \
      ac = __builtin_amdgcn_mfma_f32_32x32x16_bf16(v0.v8, pA.v8, ac, 0, 0, 0); \
      ac = __builtin_amdgcn_mfma_f32_32x32x16_bf16(v1.v8, pB.v8, ac, 0, 0, 0); \
      ac = __builtin_amdgcn_mfma_f32_32x32x16_bf16(v2.v8, pC.v8, ac, 0, 0, 0); \
      ac = __builtin_amdgcn_mfma_f32_32x32x16_bf16(v3.v8, pD.v8, ac, 0, 0, 0); \
      accO[dh] = ac;                                                         \
    }                                                                        \
  }

#define ATTN_PHASE(B, SB, VMSTR, DOST)                                       \
  WAIT_BARRIER(VMSTR)                                                        \
  if (DOST) { ATTN_STAGE(SB) }                                               \
  ATTN_COMPUTE(B)

__global__ __launch_bounds__(256) void attn_mfma_kernel(
    const unsigned short* __restrict__ Qb, const unsigned short* __restrict__ Kb,
    const unsigned short* __restrict__ Vb, unsigned short* __restrict__ Abf) {
  __shared__ unsigned short k_l[4 * 4096];  // 32 KiB
  __shared__ unsigned short v_l[4 * 4096];  // 32 KiB
  const int t = threadIdx.x;
  const int w = t >> 6;
  const int l = t & 63;
  const int n = l & 31;
  const int h = l >> 5;
  const int bid = blockIdx.x;
  const int gidx = (bid & 7) * 64 + (bid >> 3);  // XCD-contiguous bn
  const int bn = gidx >> 5;
  const int q0 = (gidx & 31) * 128 + w * 32;

  // Q fragments: qf[s] = Q[q0+n][s*16 + 8h .. +8]
  bf16x8 qf[4];
#pragma unroll
  for (int s = 0; s < 4; ++s)
    qf[s] = *(const bf16x8*)&Qb[((size_t)bn * HW_ + q0 + n) * 64 + s * 16 + h * 8];

  // hoisted LDS offsets (ushort units)
  const int n7 = n & 7;
  const int rowKA = n * 64;
  const int rowKB = (32 + n) * 64;
  int kox[4];
#pragma unroll
  for (int s = 0; s < 4; ++s) kox[s] = ((2 * s + h) ^ n7) * 8;
  const int h4 = 4 * h;
  const int voA0 = ((0 ^ n7) * 8) + h4, voA1 = ((1 ^ n7) * 8) + h4;
  const int voB0 = ((2 ^ n7) * 8) + h4, voB1 = ((3 ^ n7) * 8) + h4;
  const int voC0 = ((4 ^ n7) * 8) + h4, voC1 = ((5 ^ n7) * 8) + h4;
  const int voD0 = ((6 ^ n7) * 8) + h4, voD1 = ((7 ^ n7) * 8) + h4;

  const int srow = 16 * w + (l >> 3);
  const int schunk = (l & 7) ^ ((l >> 3) & 7);
  const unsigned short* gKp = Kb + ((size_t)bn * HW_ + srow) * 64 + schunk * 8;
  const unsigned short* gVp = Vb + ((size_t)bn * 64 + srow) * HW_ + schunk * 8;
  unsigned short* kst = k_l + w * 1024;
  unsigned short* vst = v_l + w * 1024;

  f32x16 accO[2] = {};
  float l_r = 0.f;
  const f32x16 zero16 = {};

  ATTN_STAGE(0)
  ATTN_STAGE(1)

  for (int t4 = 0; t4 < 15; ++t4) {
    ATTN_PHASE(0, 2, "vmcnt(4)", 1)
    ATTN_PHASE(1, 3, "vmcnt(4)", 1)
    ATTN_PHASE(2, 0, "vmcnt(4)", 1)
    ATTN_PHASE(3, 1, "vmcnt(4)", 1)
  }
  ATTN_PHASE(0, 2, "vmcnt(4)", 1)
  ATTN_PHASE(1, 3, "vmcnt(4)", 1)
  ATTN_PHASE(2, 0, "vmcnt(4)", 0)
  ATTN_PHASE(3, 0, "vmcnt(0)", 0)

  // epilogue: normalize, emit bf16 cgroup layout for proj GEMM
  const int head = bn & 3;
  const int bb = bn >> 2;
  const float lsum = l_r + __shfl_xor(l_r, 32);
  const float inv = 1.0f / lsum;
  const int pcol = q0 + n;
#pragma unroll
  for (int dh = 0; dh < 2; ++dh)
#pragma unroll
    for (int k4 = 0; k4 < 4; ++k4) {
      uint2 uu;
      uu.x = cvt_pk_bf16(accO[dh][k4 * 4 + 0] * inv, accO[dh][k4 * 4 + 1] * inv);
      uu.y = cvt_pk_bf16(accO[dh][k4 * 4 + 2] * inv, accO[dh][k4 * 4 + 3] * inv);
      const int cg = head * 8 + dh * 4 + k4;
      *(uint2*)&Abf[((size_t)(bb * 32 + cg) * HW_ + pcol) * 8 + h4] = uu;
    }
}

// ---------------- SE pooling from bf16 cgroup, p-split x2 ----------------
__global__ __launch_bounds__(256) void pool_kernel(
    const unsigned short* __restrict__ Pbf, const unsigned short* __restrict__ Gbf,
    float* __restrict__ psum, float* __restrict__ pmaxH) {
  const int cg = blockIdx.x;  // 0..31
  const int b = blockIdx.y;
  const int half = blockIdx.z;
  const int t = threadIdx.x;
  const unsigned short* P = Pbf + ((size_t)(b * 32 + cg) * HW_ + half * 2048) * 8;
  const unsigned short* G = Gbf + ((size_t)(b * 32 + cg) * HW_ + half * 2048) * 8;
  float s[16], m[16];
#pragma unroll
  for (int i = 0; i < 16; ++i) { s[i] = 0.f; m[i] = -1e30f; }
  for (int p = t; p < 2048; p += 256) {
    uint4 a = *(const uint4*)&P[(size_t)p * 8];
    uint4 gg = *(const uint4*)&G[(size_t)p * 8];
    const uint32_t ua[4] = {a.x, a.y, a.z, a.w};
    const uint32_t ug[4] = {gg.x, gg.y, gg.z, gg.w};
#pragma unroll
    for (int q = 0; q < 4; ++q) {
      const float a0 = bf_lo(ua[q]), a1 = bf_hi(ua[q]);
      const float g0 = bf_lo(ug[q]), g1 = bf_hi(ug[q]);
      s[q * 2] += a0; s[q * 2 + 1] += a1;
      m[q * 2] = fmaxf(m[q * 2], a0); m[q * 2 + 1] = fmaxf(m[q * 2 + 1], a1);
      s[8 + q * 2] += g0; s[8 + q * 2 + 1] += g1;
      m[8 + q * 2] = fmaxf(m[8 + q * 2], g0); m[8 + q * 2 + 1] = fmaxf(m[8 + q * 2 + 1], g1);
    }
  }
#pragma unroll
  for (int i = 0; i < 16; ++i)
#pragma unroll
    for (int off = 1; off < 64; off <<= 1) {
      s[i] += __shfl_xor(s[i], off);
      m[i] = fmaxf(m[i], __shfl_xor(m[i], off));
    }
  __shared__ float red[4][32];
  const int wv = t >> 6;
  if ((t & 63) == 0) {
#pragma unroll
    for (int i = 0; i < 16; ++i) { red[wv][i] = s[i]; red[wv][16 + i] = m[i]; }
  }
  __syncthreads();
  if (t < 32) {
    const float v0 = red[0][t], v1 = red[1][t], v2 = red[2][t], v3 = red[3][t];
    if (t < 16) {
      const int ch = (t < 8) ? cg * 8 + t : 256 + cg * 8 + (t - 8);
      psum[half * 2048 + b * 512 + ch] = v0 + v1 + v2 + v3;
    } else {
      const int i = t - 16;
      const int ch = (i < 8) ? cg * 8 + i : 256 + cg * 8 + (i - 8);
      pmaxH[half * 2048 + b * 512 + ch] = fmaxf(fmaxf(v0, v1), fmaxf(v2, v3));
    }
  }
}

// ---------------- SE MLP (merges pool halves) ----------------
__global__ __launch_bounds__(256) void se_kernel(
    const float* __restrict__ psum, const float* __restrict__ pmaxH,
    const float* __restrict__ w1, const float* __restrict__ w2,
    float* __restrict__ wch) {
  const int b = blockIdx.x;
  const int t = threadIdx.x;
  __shared__ float za[512], zm[512], hs[64];
  za[t] = (psum[b * 512 + t] + psum[2048 + b * 512 + t]) * (1.f / 4096.f);
  za[256 + t] = (psum[b * 512 + 256 + t] + psum[2048 + b * 512 + 256 + t]) * (1.f / 4096.f);
  zm[t] = fmaxf(pmaxH[b * 512 + t], pmaxH[2048 + b * 512 + t]);
  zm[256 + t] = fmaxf(pmaxH[b * 512 + 256 + t], pmaxH[2048 + b * 512 + 256 + t]);
  __syncthreads();
  if (t < 64) {
    float ha = 0.f, hm = 0.f;
    for (int c = 0; c < 512; ++c) {
      const float w = w1[t * 512 + c];
      ha += w * za[c];
      hm += w * zm[c];
    }
    hs[t] = fmaxf(ha, 0.f) + fmaxf(hm, 0.f);
  }
  __syncthreads();
  for (int o = t; o < 512; o += 256) {
    float acc = 0.f;
#pragma unroll
    for (int hh = 0; hh < 64; ++hh) acc += hs[hh] * w2[o * 64 + hh];
    wch[b * 512 + o] = 1.f / (1.f + __expf(-acc));
  }
}

// ---------------- spatial-attention input: 4 ch-slices per block ----------------
__global__ __launch_bounds__(256) void sa_reduce_kernel(
    const unsigned short* __restrict__ Pbf, const unsigned short* __restrict__ Gbf,
    const float* __restrict__ wch, float* __restrict__ sa_in) {
  const int b = blockIdx.y;
  const int t = threadIdx.x;
  const int px = t & 63;
  const int sl = t >> 6;
  const int p = blockIdx.x * 64 + px;
  __shared__ float wl[512];
  __shared__ float sred[4][64], mred[4][64];
  wl[t] = wch[b * 512 + t];
  wl[256 + t] = wch[b * 512 + 256 + t];
  __syncthreads();
  float s = 0.f, mx = -1e30f;
#pragma unroll 4
  for (int k = 0; k < 16; ++k) {
    const int chunk = sl * 16 + k;
    const unsigned short* src = (chunk < 32)
        ? &Pbf[((size_t)(b * 32 + chunk) * HW_ + p) * 8]
        : &Gbf[((size_t)(b * 32 + (chunk - 32)) * HW_ + p) * 8];
    uint4 a = *(const uint4*)src;
    const uint32_t u[4] = {a.x, a.y, a.z, a.w};
#pragma unroll
    for (int q = 0; q < 4; ++q) {
      const float v0 = bf_lo(u[q]) * wl[chunk * 8 + q * 2];
      const float v1 = bf_hi(u[q]) * wl[chunk * 8 + q * 2 + 1];
      s += v0 + v1;
      mx = fmaxf(mx, fmaxf(v0, v1));
    }
  }
  sred[sl][px] = s;
  mred[sl][px] = mx;
  __syncthreads();
  if (sl == 0) {
    const float S = sred[0][px] + sred[1][px] + sred[2][px] + sred[3][px];
    const float M = fmaxf(fmaxf(mred[0][px], mred[1][px]), fmaxf(mred[2][px], mred[3][px]));
    sa_in[((size_t)b * 2 + 0) * HW_ + p] = S * (1.f / 512.f);
    sa_in[((size_t)b * 2 + 1) * HW_ + p] = M;
  }
}

// ---------------- 7x7 spatial conv + sigmoid -> wsp ----------------
__global__ __launch_bounds__(256) void sa_conv_kernel(
    const float* __restrict__ sa_in, const float* __restrict__ sa_w,
    float* __restrict__ wsp) {
  const int b = blockIdx.y;
  const int t = threadIdx.x;
  __shared__ float pl[2][64][64];
  __shared__ float wl[98];
  for (int e = t; e < 8192; e += 256) ((float*)pl)[e] = sa_in[(size_t)b * 8192 + e];
  if (t < 98) wl[t] = sa_w[t];
  __syncthreads();
  const int pix = blockIdx.x * 256 + t;
  const int y = pix >> 6, x = pix & 63;
  float acc = 0.f;
#pragma unroll
  for (int ic = 0; ic < 2; ++ic)
#pragma unroll
    for (int ky = 0; ky < 7; ++ky) {
      const int yy = y + ky - 3;
      if (yy < 0 || yy > 63) continue;
#pragma unroll
      for (int kx = 0; kx < 7; ++kx) {
        const int xx = x + kx - 3;
        if (xx < 0 || xx > 63) continue;
        acc += pl[ic][yy][xx] * wl[ic * 49 + ky * 7 + kx];
      }
    }
  wsp[(size_t)b * HW_ + pix] = 1.f / (1.f + __expf(-acc));
}

// ---------------- gate: catg[b][yp:66][xi:80][ic:512] bf16 (NHWC, halo=0) ----------------
__global__ __launch_bounds__(256) void gate_kernel(
    const unsigned short* __restrict__ Pbf, const unsigned short* __restrict__ Gbf,
    const float* __restrict__ wch, const float* __restrict__ wsp,
    unsigned short* __restrict__ catg) {
  const int yp = blockIdx.x;  // 0..65
  const int b = blockIdx.y;
  const int t = threadIdx.x;
  unsigned short* rowp = catg + ((size_t)b * 66 + yp) * 80 * 512;
  if (yp == 0 || yp == 65) {
    short8v z = {};
    for (int m = t; m < 5120; m += 256) *(short8v*)&rowp[m * 8] = z;
    return;
  }
  const int y = yp - 1;
  __shared__ unsigned short tile[64][512];  // [x][ch], chunk XOR-swizzled by (x&7)
  __shared__ float wchl[512];
  __shared__ float wspl[64];
  for (int e = t; e < 512; e += 256) wchl[e] = wch[b * 512 + e];
  if (t < 64) wspl[t] = wsp[(size_t)b * HW_ + y * 64 + t];
  {
    short8v z = {};
    for (int m = t; m < 1024; m += 256) {
      const int col = m >> 6;
      const int xi = (col < 8) ? col : (col + 64);
      *(short8v*)&rowp[(size_t)xi * 512 + (m & 63) * 8] = z;
    }
  }
  __syncthreads();
  const int x = t & 63;
  const int cs = t >> 6;
  const float wx = wspl[x];
#pragma unroll
  for (int k = 0; k < 16; ++k) {
    const int chunk = cs * 16 + k;
    const unsigned short* src = (chunk < 32)
        ? &Pbf[((size_t)(b * 32 + chunk) * HW_ + y * 64 + x) * 8]
        : &Gbf[((size_t)(b * 32 + (chunk - 32)) * HW_ + y * 64 + x) * 8];
    uint4 a = *(const uint4*)src;
    const uint32_t u[4] = {a.x, a.y, a.z, a.w};
    uint32_t o[4];
#pragma unroll
    for (int q = 0; q < 4; ++q) {
      const float lo = bf_lo(u[q]) * wchl[chunk * 8 + q * 2] * wx;
      const float hi = bf_hi(u[q]) * wchl[chunk * 8 + q * 2 + 1] * wx;
      o[q] = cvt_pk_bf16(lo, hi);
    }
    uint4 ov = {o[0], o[1], o[2], o[3]};
    *(uint4*)&tile[x][(chunk ^ (x & 7)) * 8] = ov;
  }
  __syncthreads();
#pragma unroll
  for (int j = 0; j < 16; ++j) {
    const int xi = (t >> 6) + 4 * j;
    const int c8 = t & 63;
    uint4 v = *(const uint4*)&tile[xi][(c8 ^ (xi & 7)) * 8];
    *(uint4*)&rowp[(size_t)(xi + 8) * 512 + c8 * 8] = v;
  }
}

// ---------------- fuse conv via MFMA: 32-oc tiles, 512 blocks, XCD-grouped ----------------
__global__ __launch_bounds__(256) void fuse_mfma_kernel(
    const unsigned short* __restrict__ catg, const unsigned short* __restrict__ wt,
    const float* __restrict__ bn_g, const float* __restrict__ bn_b,
    const float* __restrict__ bn_m, const float* __restrict__ bn_v,
    float* __restrict__ out) {
  __shared__ unsigned short X_l[2][6][2][80][8];  // 30 KiB
  __shared__ unsigned short W_l[2][9][2][32][8];  // 18 KiB
  __shared__ float invl[32], shl[32];
  const int t = threadIdx.x;
  const int w = t >> 6;
  const int l = t & 63;
  const int n = l & 31;
  const int g = l >> 5;
  const int i = blockIdx.x;
  const int xcd = i & 7, slot = i >> 3;
  const int ocB = slot & 7;
  const int yb = xcd + 8 * (slot >> 3);
  const int y0 = (yb & 15) * 4;
  const int o0 = ocB * 32;
  const int b = yb >> 4;

  if (t < 32) {
    const float iv = bn_g[o0 + t] * rsqrtf(bn_v[o0 + t] + 1e-5f);
    invl[t] = iv;
    shl[t] = bn_b[o0 + t] - bn_m[o0 + t] * iv;
  }

  const unsigned short* catb = catg + ((size_t)b * 66 + y0) * 80 * 512;

  auto stageX = [&](int bi, int ic0) {
    for (int wc = w; wc < 15; wc += 4) {
      const int m = wc * 64 + l;
      const int lr = m / 160;
      const int rem = m - lr * 160;
      const int half = rem / 80;
      const int xi = rem - half * 80;
      gld_lds16(catb + ((size_t)lr * 80 + xi) * 512 + ic0 + half * 8,
                &X_l[bi][0][0][0][0] + (size_t)wc * 512);
    }
  };
  auto stageW = [&](int bi, int ic0) {
    for (int wc = w; wc < 9; wc += 4) {
      const int m = wc * 64 + l;
      const int tap = m >> 6;
      const int rem = m & 63;
      const int half = rem >> 5;
      const int oc = rem & 31;
      gld_lds16(wt + ((size_t)tap * 256 + o0 + oc) * 512 + ic0 + half * 8,
                &W_l[bi][0][0][0][0] + (size_t)wc * 512);
    }
  };

  f32x16 acc[2] = {};

  stageX(0, 0);
  stageW(0, 0);
  int buf = 0;
  for (int ks = 0; ks < 32; ++ks) {
    asm volatile("s_waitcnt vmcnt(0)" ::: "memory");
    __syncthreads();
    if (ks < 31) {
      stageX(buf ^ 1, (ks + 1) * 16);
      stageW(buf ^ 1, (ks + 1) * 16);
    }
#pragma unroll
    for (int ky = 0; ky < 3; ++ky) {
      const int lr = w + ky;
#pragma unroll
      for (int kx = 0; kx < 3; ++kx) {
        const int tap = ky * 3 + kx;
        bf16x8 a0 = *(const bf16x8*)&W_l[buf][tap][g][n][0];
        bf16x8 b0 = *(const bf16x8*)&X_l[buf][lr][g][n + kx + 7][0];
        bf16x8 b1 = *(const bf16x8*)&X_l[buf][lr][g][32 + n + kx + 7][0];
        acc[0] = __builtin_amdgcn_mfma_f32_32x32x16_bf16(a0, b0, acc[0], 0, 0, 0);
        acc[1] = __builtin_amdgcn_mfma_f32_32x32x16_bf16(a0, b1, acc[1], 0, 0, 0);
      }
    }
    buf ^= 1;
  }

#pragma unroll
  for (int pf = 0; pf < 2; ++pf)
#pragma unroll
    for (int r = 0; r < 16; ++r) {
      const int row = (r & 3) + 8 * (r >> 2) + 4 * g;
      const float yv = acc[pf][r] * invl[row] + shl[row];
      const float ov = yv > 0.f ? yv : 0.2f * yv;
      out[((size_t)b * 256 + o0 + row) * HW_ + (size_t)(y0 + w) * 64 + pf * 32 + n] = ov;
    }
}

extern "C" void kernel_launch(void* const* d_in, const int* in_sizes, int n_in,
                              void* d_out, int out_size, void* d_ws, size_t ws_size,
                              hipStream_t stream) {
  const float* color  = (const float*)d_in[0];
  const float* gray   = (const float*)d_in[1];
  const float* Wq     = (const float*)d_in[2];
  const float* Wk     = (const float*)d_in[3];
  const float* Wv     = (const float*)d_in[4];
  const float* Wproj  = (const float*)d_in[5];
  const float* ca_w1  = (const float*)d_in[6];
  const float* ca_w2  = (const float*)d_in[7];
  const float* sa_w   = (const float*)d_in[8];
  const float* fuse_w = (const float*)d_in[9];
  const float* bn_g   = (const float*)d_in[10];
  const float* bn_b   = (const float*)d_in[11];
  const float* bn_m   = (const float*)d_in[12];
  const float* bn_v   = (const float*)d_in[13];
  float* out = (float*)d_out;

  char* ws = (char*)d_ws;
  unsigned short* Cbf = (unsigned short*)(ws);
  unsigned short* Gbf = (unsigned short*)(ws + (8u << 20));
  unsigned short* Qbf = (unsigned short*)(ws + (16u << 20));
  unsigned short* Kbf = (unsigned short*)(ws + (24u << 20));
  unsigned short* Vbf = (unsigned short*)(ws + (32u << 20));
  unsigned short* Abf = (unsigned short*)(ws);
  unsigned short* Pbf = (unsigned short*)(ws + (16u << 20));
  unsigned short* catg = (unsigned short*)(ws + (24u << 20));
  unsigned short* WqB = (unsigned short*)(ws + (45u << 20));
  unsigned short* WkB = WqB + 65536;
  unsigned short* WvB = WkB + 65536;
  unsigned short* WpB = WvB + 65536;
  unsigned short* Wt  = (unsigned short*)(ws + (45u << 20) + (1u << 19));
  float* psum  = (float*)(ws + (48u << 20));  // [2][2048]
  float* pmaxH = psum + 4096;                 // [2][2048]
  float* wch   = pmaxH + 4096;
  float* sa_in = wch + 2048;     // 32768
  float* wsp   = sa_in + 32768;  // 16384
  (void)in_sizes; (void)n_in; (void)out_size; (void)ws_size;

  const float qscale = 0.125f * 1.44269504f;

  prep_kernel<<<dim3(640), 256, 0, stream>>>(Wq, Wk, Wv, Wproj, fuse_w,
                                             WqB, WkB, WvB, WpB, Wt);
  xconv_kernel<<<dim3(2048), 256, 0, stream>>>(color, Cbf);
  xconv_kernel<<<dim3(2048), 256, 0, stream>>>(gray, Gbf);

  dim3 g_gemm(32, 4, 4);
  gemm_mfma_kernel<<<g_gemm, 256, 0, stream>>>(Cbf, WqB, Qbf, 1, qscale);
  gemm_mfma_kernel<<<g_gemm, 256, 0, stream>>>(Gbf, WkB, Kbf, 1, 1.0f);
  gemm_mfma_kernel<<<g_gemm, 256, 0, stream>>>(Gbf, WvB, Vbf, 2, 1.0f);
  attn_mfma_kernel<<<dim3(512), 256, 0, stream>>>(Qbf, Kbf, Vbf, Abf);
  gemm_mfma_kernel<<<g_gemm, 256, 0, stream>>>(Abf, WpB, Pbf, 3, 1.0f);

  pool_kernel<<<dim3(32, 4, 2), 256, 0, stream>>>(Pbf, Gbf, psum, pmaxH);
  se_kernel<<<dim3(4), 256, 0, stream>>>(psum, pmaxH, ca_w1, ca_w2, wch);
  sa_reduce_kernel<<<dim3(64, 4), 256, 0, stream>>>(Pbf, Gbf, wch, sa_in);
  sa_conv_kernel<<<dim3(16, 4), 256, 0, stream>>>(sa_in, sa_w, wsp);
  gate_kernel<<<dim3(66, 4), 256, 0, stream>>>(Pbf, Gbf, wch, wsp, catg);
  fuse_mfma_kernel<<<dim3(512), 256, 0, stream>>>(catg, Wt, bn_g, bn_b, bn_m, bn_v, out);
}

// Round 10
// 252.926 us; speedup vs baseline: 1.0317x; 1.0317x over previous
//
#include <hip/hip_runtime.h>
#include <hip/hip_bf16.h>
#include <stdint.h>

#define HW_ 4096

typedef short bf16x8 __attribute__((ext_vector_type(8)));
typedef short short4v __attribute__((ext_vector_type(4)));
typedef short short8v __attribute__((ext_vector_type(8)));
typedef float f32x4 __attribute__((ext_vector_type(4)));
typedef float f32x16 __attribute__((ext_vector_type(16)));
typedef uint32_t u32x4 __attribute__((ext_vector_type(4)));

__device__ inline unsigned short f2bf(float x) {
  uint32_t u = __builtin_bit_cast(uint32_t, x);
  uint32_t r = ((u >> 16) & 1u) + 0x7fffu;
  return (unsigned short)((u + r) >> 16);
}
__device__ inline uint32_t cvt_pk_bf16(float lo, float hi) {
  uint32_t r;
  asm("v_cvt_pk_bf16_f32 %0, %1, %2" : "=v"(r) : "v"(lo), "v"(hi));
  return r;
}
__device__ inline float bf_lo(uint32_t u) { return __builtin_bit_cast(float, u << 16); }
__device__ inline float bf_hi(uint32_t u) { return __builtin_bit_cast(float, u & 0xffff0000u); }
__device__ inline void gld_lds16(const unsigned short* g, unsigned short* l) {
  __builtin_amdgcn_global_load_lds((const __attribute__((address_space(1))) void*)g,
                                   (__attribute__((address_space(3))) void*)l, 16, 0, 0);
}

// fused waitcnt+barrier: single asm block with memory clobber so NO memory op
// (ds_read of the compute, gld_lds16 of the stage) can cross the barrier.
// Raw __builtin_amdgcn_s_barrier() alone is NOT an IR-level memory fence.
#define WAIT_BARRIER(VMSTR)                                                  \
  asm volatile("s_waitcnt " VMSTR "\n\ts_barrier" ::: "memory");             \
  __builtin_amdgcn_sched_barrier(0);

// ---------------- xconv: fp32 [b][c][p] -> bf16 cgroup layout [(b*32+cg)][p][e] ----------------
__global__ __launch_bounds__(256) void xconv_kernel(
    const float* __restrict__ X, unsigned short* __restrict__ Y) {
  const int i = blockIdx.x * 256 + threadIdx.x;
  const int p = i & 4095;
  const int cg = (i >> 12) & 31;
  const int b = i >> 17;
  const float* src = X + ((size_t)b * 256 + cg * 8) * HW_ + p;
  float v[8];
#pragma unroll
  for (int e = 0; e < 8; ++e) v[e] = src[(size_t)e * HW_];
  uint4 o;
  o.x = cvt_pk_bf16(v[0], v[1]);
  o.y = cvt_pk_bf16(v[2], v[3]);
  o.z = cvt_pk_bf16(v[4], v[5]);
  o.w = cvt_pk_bf16(v[6], v[7]);
  *(uint4*)&Y[((size_t)(b * 32 + cg) * HW_ + p) * 8] = o;
}

// ---------------- prep: 4x wconv (fp32 W[o][c] -> bf16 [cg][o][e]) + wtrans ----------------
__global__ __launch_bounds__(256) void prep_kernel(
    const float* __restrict__ Wq, const float* __restrict__ Wk,
    const float* __restrict__ Wv, const float* __restrict__ Wp,
    const float* __restrict__ fw,
    unsigned short* __restrict__ WqB, unsigned short* __restrict__ WkB,
    unsigned short* __restrict__ WvB, unsigned short* __restrict__ WpB,
    unsigned short* __restrict__ wt) {
  const int blk = blockIdx.x;
  if (blk < 128) {
    const int which = blk >> 5;
    const float* W = which == 0 ? Wq : which == 1 ? Wk : which == 2 ? Wv : Wp;
    unsigned short* Y = which == 0 ? WqB : which == 1 ? WkB : which == 2 ? WvB : WpB;
    const int i = (blk & 31) * 256 + threadIdx.x;  // 8192
    const int o = i & 255;
    const int cg = i >> 8;
    float4 a = *(const float4*)&W[(size_t)o * 256 + cg * 8];
    float4 bq = *(const float4*)&W[(size_t)o * 256 + cg * 8 + 4];
    uint4 ov;
    ov.x = cvt_pk_bf16(a.x, a.y);
    ov.y = cvt_pk_bf16(a.z, a.w);
    ov.z = cvt_pk_bf16(bq.x, bq.y);
    ov.w = cvt_pk_bf16(bq.z, bq.w);
    *(uint4*)&Y[((size_t)cg * 256 + o) * 8] = ov;
  } else {
    const size_t i = (size_t)(blk - 128) * 256 + threadIdx.x;  // 256*512
    const int oc = (int)(i >> 9);
    const int ic = (int)(i & 511);
    const float* src = fw + i * 9;
#pragma unroll
    for (int tap = 0; tap < 9; ++tap)
      wt[((size_t)tap * 256 + oc) * 512 + ic] = f2bf(src[tap]);
  }
}

// ---------------- MFMA GEMM, counted-vmcnt 4-buf pipeline ----------------
// Xbf: [(b*32+cg)][p][e], Wbf: [cg][o][e]. Block 64o x 128p, 4 waves.
// mode 1: bf16 [b*4+oy][p][dd]*oscale; 3: bf16 cgroup.
#define GSTAGE(KS, BUF)                                                       \
  gld_lds16(Xb + ((size_t)((KS) * 2 + (t >> 7)) * HW_ + p0 + (t & 127)) * 8,  \
            &X_l[BUF][0][0][0] + (size_t)t * 8);
#define GCOMP(KS)                                                             \
  {                                                                           \
    bf16x8 af = *(const bf16x8*)&W_l[(KS) * 2 + g32][wo * 32 + n][0];         \
    bf16x8 b0 = *(const bf16x8*)&X_l[(KS) & 3][g32][wp * 64 + n][0];          \
    bf16x8 b1 = *(const bf16x8*)&X_l[(KS) & 3][g32][wp * 64 + 32 + n][0];     \
    acc[0] = __builtin_amdgcn_mfma_f32_32x32x16_bf16(af, b0, acc[0], 0, 0, 0);\
    acc[1] = __builtin_amdgcn_mfma_f32_32x32x16_bf16(af, b1, acc[1], 0, 0, 0);\
  }

__global__ __launch_bounds__(256) void gemm_mfma_kernel(
    const unsigned short* __restrict__ Xbf, const unsigned short* __restrict__ Wbf,
    void* __restrict__ Yv, int mode, float oscale) {
  __shared__ unsigned short W_l[32][64][8];     // 32KB, staged once
  __shared__ unsigned short X_l[4][2][128][8];  // 16KB ring
  const int t = threadIdx.x;
  const int w = t >> 6;
  const int l = t & 63;
  const int n = l & 31;
  const int g32 = l >> 5;
  const int p0 = blockIdx.x * 128;
  const int o0 = blockIdx.y * 64;
  const int b = blockIdx.z;
  const int wo = w >> 1, wp = w & 1;
  const unsigned short* Xb = Xbf + (size_t)b * 32 * HW_ * 8;

#pragma unroll
  for (int j = 0; j < 8; ++j) {
    const int i = j * 256 + t;
    gld_lds16(Wbf + ((size_t)(i >> 6) * 256 + o0 + (i & 63)) * 8,
              &W_l[0][0][0] + (size_t)i * 8);
  }
  GSTAGE(0, 0)
  GSTAGE(1, 1)
  GSTAGE(2, 2)

  f32x16 acc[2] = {};
  for (int ks = 0; ks < 13; ++ks) {
    WAIT_BARRIER("vmcnt(2)")
    GSTAGE(ks + 3, (ks + 3) & 3)
    GCOMP(ks)
  }
  WAIT_BARRIER("vmcnt(2)")
  GCOMP(13)
  WAIT_BARRIER("vmcnt(1)")
  GCOMP(14)
  WAIT_BARRIER("vmcnt(0)")
  GCOMP(15)

  if (mode == 1) {
    unsigned short* Y = (unsigned short*)Yv;
    const size_t bh = (size_t)b * 4 + blockIdx.y;
#pragma unroll
    for (int pf = 0; pf < 2; ++pf) {
      const int p = p0 + wp * 64 + pf * 32 + n;
      unsigned short* dst = Y + (bh * HW_ + p) * 64 + wo * 32 + 4 * g32;
#pragma unroll
      for (int q = 0; q < 4; ++q) {
        uint2 uu;
        uu.x = cvt_pk_bf16(acc[pf][q * 4 + 0] * oscale, acc[pf][q * 4 + 1] * oscale);
        uu.y = cvt_pk_bf16(acc[pf][q * 4 + 2] * oscale, acc[pf][q * 4 + 3] * oscale);
        *(uint2*)&dst[8 * q] = uu;
      }
    }
  } else {  // mode 3: bf16 cgroup [(b*32+cg)][p][e]
    unsigned short* Y = (unsigned short*)Yv;
    const int cgb = (o0 + wo * 32) >> 3;
#pragma unroll
    for (int pf = 0; pf < 2; ++pf) {
      const int p = p0 + wp * 64 + pf * 32 + n;
#pragma unroll
      for (int q = 0; q < 4; ++q) {
        uint2 uu;
        uu.x = cvt_pk_bf16(acc[pf][q * 4 + 0], acc[pf][q * 4 + 1]);
        uu.y = cvt_pk_bf16(acc[pf][q * 4 + 2], acc[pf][q * 4 + 3]);
        *(uint2*)&Y[((size_t)(b * 32 + cgb + q) * HW_ + p) * 8 + 4 * g32] = uu;
      }
    }
  }
}

// ---------------- fused K+V GEMM: stages X once, two W tiles ----------------
#define GCOMP_KV(KS)                                                          \
  {                                                                           \
    bf16x8 afk = *(const bf16x8*)&W_l[0][(KS) * 2 + g32][wo * 32 + n][0];     \
    bf16x8 afv = *(const bf16x8*)&W_l[1][(KS) * 2 + g32][wo * 32 + n][0];     \
    bf16x8 b0 = *(const bf16x8*)&X_l[(KS) & 3][g32][wp * 64 + n][0];          \
    bf16x8 b1 = *(const bf16x8*)&X_l[(KS) & 3][g32][wp * 64 + 32 + n][0];     \
    accK[0] = __builtin_amdgcn_mfma_f32_32x32x16_bf16(afk, b0, accK[0], 0, 0, 0); \
    accK[1] = __builtin_amdgcn_mfma_f32_32x32x16_bf16(afk, b1, accK[1], 0, 0, 0); \
    accV[0] = __builtin_amdgcn_mfma_f32_32x32x16_bf16(afv, b0, accV[0], 0, 0, 0); \
    accV[1] = __builtin_amdgcn_mfma_f32_32x32x16_bf16(afv, b1, accV[1], 0, 0, 0); \
  }

__global__ __launch_bounds__(256) void gemm_kv_kernel(
    const unsigned short* __restrict__ Xbf, const unsigned short* __restrict__ WkB,
    const unsigned short* __restrict__ WvB, unsigned short* __restrict__ Kout,
    unsigned short* __restrict__ Vout) {
  __shared__ unsigned short W_l[2][32][64][8];  // 64KB, staged once
  __shared__ unsigned short X_l[4][2][128][8];  // 16KB ring
  const int t = threadIdx.x;
  const int w = t >> 6;
  const int l = t & 63;
  const int n = l & 31;
  const int g32 = l >> 5;
  const int p0 = blockIdx.x * 128;
  const int o0 = blockIdx.y * 64;
  const int b = blockIdx.z;
  const int wo = w >> 1, wp = w & 1;
  const unsigned short* Xb = Xbf + (size_t)b * 32 * HW_ * 8;

#pragma unroll
  for (int j = 0; j < 16; ++j) {
    const int i = j * 256 + t;          // 0..4095
    const int ii = i & 2047;
    const unsigned short* Wsrc = (i >> 11) ? WvB : WkB;
    gld_lds16(Wsrc + ((size_t)(ii >> 6) * 256 + o0 + (ii & 63)) * 8,
              &W_l[0][0][0][0] + (size_t)i * 8);
  }
  GSTAGE(0, 0)
  GSTAGE(1, 1)
  GSTAGE(2, 2)

  f32x16 accK[2] = {};
  f32x16 accV[2] = {};
  for (int ks = 0; ks < 13; ++ks) {
    WAIT_BARRIER("vmcnt(2)")
    GSTAGE(ks + 3, (ks + 3) & 3)
    GCOMP_KV(ks)
  }
  WAIT_BARRIER("vmcnt(2)")
  GCOMP_KV(13)
  WAIT_BARRIER("vmcnt(1)")
  GCOMP_KV(14)
  WAIT_BARRIER("vmcnt(0)")
  GCOMP_KV(15)

  // K epilogue: bf16 [b*4+oy][p][dd]
  const size_t bh = (size_t)b * 4 + blockIdx.y;
#pragma unroll
  for (int pf = 0; pf < 2; ++pf) {
    const int p = p0 + wp * 64 + pf * 32 + n;
    unsigned short* dst = Kout + (bh * HW_ + p) * 64 + wo * 32 + 4 * g32;
#pragma unroll
    for (int q = 0; q < 4; ++q) {
      uint2 uu;
      uu.x = cvt_pk_bf16(accK[pf][q * 4 + 0], accK[pf][q * 4 + 1]);
      uu.y = cvt_pk_bf16(accK[pf][q * 4 + 2], accK[pf][q * 4 + 3]);
      *(uint2*)&dst[8 * q] = uu;
    }
  }
  // V epilogue: bf16 [b][c][p]
#pragma unroll
  for (int pf = 0; pf < 2; ++pf) {
    const int p = p0 + wp * 64 + pf * 32 + n;
#pragma unroll
    for (int r = 0; r < 16; ++r) {
      const int m = (r & 3) + 8 * (r >> 2) + 4 * g32;
      Vout[((size_t)b * 256 + o0 + wo * 32 + m) * HW_ + p] = f2bf(accV[pf][r]);
    }
  }
}

// ---------------- MFMA flash attention: 32x32x16, 4-buf counted-vmcnt + setprio ----------------
#define ATTN_STAGE(SB)                                                       \
  {                                                                          \
    gld_lds16(gKp, kst + (SB) * 4096);                                       \
    gld_lds16(gKp + 8 * 64, kst + (SB) * 4096 + 512);                        \
    gld_lds16(gVp, vst + (SB) * 4096);                                       \
    gld_lds16(gVp + (size_t)8 * HW_, vst + (SB) * 4096 + 512);               \
    gKp += 4096;                                                             \
    gVp += 64;                                                               \
  }

#define ATTN_COMPUTE(BUF)                                                    \
  {                                                                          \
    f32x16 aS0 = zero16, aS1 = zero16;                                       \
    __builtin_amdgcn_s_setprio(1);                                           \
    _Pragma("unroll") for (int s = 0; s < 4; ++s) {                          \
      bf16x8 kf0 = *(const bf16x8*)&k_l[(BUF) * 4096 + rowKA + kox[s]];      \
      bf16x8 kf1 = *(const bf16x8*)&k_l[(BUF) * 4096 + rowKB + kox[s]];      \
      aS0 = __builtin_amdgcn_mfma_f32_32x32x16_bf16(kf0, qf[s], aS0, 0, 0, 0); \
      aS1 = __builtin_amdgcn_mfma_f32_32x32x16_bf16(kf1, qf[s], aS1, 0, 0, 0); \
    }                                                                        \
    __builtin_amdgcn_s_setprio(0);                                           \
    float ex0[16], ex1[16];                                                  \
    _Pragma("unroll") for (int r = 0; r < 16; ++r) {                         \
      ex0[r] = __builtin_amdgcn_exp2f(aS0[r]);                               \
      ex1[r] = __builtin_amdgcn_exp2f(aS1[r]);                               \
    }                                                                        \
    float rsp0 = 0.f, rsp1 = 0.f, rsp2 = 0.f, rsp3 = 0.f;                    \
    _Pragma("unroll") for (int r = 0; r < 16; r += 4) {                      \
      rsp0 += ex0[r + 0] + ex1[r + 0];                                       \
      rsp1 += ex0[r + 1] + ex1[r + 1];                                       \
      rsp2 += ex0[r + 2] + ex1[r + 2];                                       \
      rsp3 += ex0[r + 3] + ex1[r + 3];                                       \
    }                                                                        \
    l_r += (rsp0 + rsp1) + (rsp2 + rsp3);                                    \
    union { u32x4 u4; bf16x8 v8; } pA, pB, pC, pD;                           \
    pA.u4 = (u32x4){cvt_pk_bf16(ex0[0], ex0[1]), cvt_pk_bf16(ex0[2], ex0[3]),    \
                    cvt_pk_bf16(ex0[4], ex0[5]), cvt_pk_bf16(ex0[6], ex0[7])};   \
    pB.u4 = (u32x4){cvt_pk_bf16(ex0[8], ex0[9]), cvt_pk_bf16(ex0[10], ex0[11]),  \
                    cvt_pk_bf16(ex0[12], ex0[13]), cvt_pk_bf16(ex0[14], ex0[15])};\
    pC.u4 = (u32x4){cvt_pk_bf16(ex1[0], ex1[1]), cvt_pk_bf16(ex1[2], ex1[3]),    \
                    cvt_pk_bf16(ex1[4], ex1[5]), cvt_pk_bf16(ex1[6], ex1[7])};   \
    pD.u4 = (u32x4){cvt_pk_bf16(ex1[8], ex1[9]), cvt_pk_bf16(ex1[10], ex1[11]),  \
                    cvt_pk_bf16(ex1[12], ex1[13]), cvt_pk_bf16(ex1[14], ex1[15])};\
    __builtin_amdgcn_s_setprio(1);                                           \
    _Pragma("unroll") for (int dh = 0; dh < 2; ++dh) {                       \
      const int rw = (BUF) * 4096 + (dh * 32 + n) * 64;                      \
      union { short4v h2[2]; bf16x8 v8; } v0, v1, v2, v3;                    \
      v0.h2[0] = *(const short4v*)&v_l[rw + voA0];                           \
      v0.h2[1] = *(const short4v*)&v_l[rw + voA1];                           \
      v1.h2[0] = *(const short4v*)&v_l[rw + voB0];                           \
      v1.h2[1] = *(const short4v*)&v_l[rw + voB1];                           \
      v2.h2[0] = *(const short4v*)&v_l[rw + voC0];                           \
      v2.h2[1] = *(const short4v*)&v_l[rw + voC1];                           \
      v3.h2[0] = *(const short4v*)&v_l[rw + voD0];                           \
      v3.h2[1] = *(const short4v*)&v_l[rw + voD1];                           \
      f32x16 ac = accO[dh];                                                  \
      ac = __builtin_amdgcn_mfma_f32_32x32x16_bf16(v0.v8, pA.v8, ac, 0, 0, 0); \
      ac = __builtin_amdgcn_mfma_f32_32x32x16_bf16(v1.v8, pB.v8, ac, 0, 0, 0); \
      ac = __builtin_amdgcn_mfma_f32_32x32x16_bf16(v2.v8, pC.v8, ac, 0, 0, 0); \
      ac = __builtin_amdgcn_mfma_f32_32x32x16_bf16(v3.v8, pD.v8, ac, 0, 0, 0); \
      accO[dh] = ac;                                                         \
    }                                                                        \
    __builtin_amdgcn_s_setprio(0);                                           \
  }

#define ATTN_PHASE(B, SB, VMSTR, DOST)                                       \
  WAIT_BARRIER(VMSTR)                                                        \
  if (DOST) { ATTN_STAGE(SB) }                                               \
  ATTN_COMPUTE(B)

__global__ __launch_bounds__(256) void attn_mfma_kernel(
    const unsigned short* __restrict__ Qb, const unsigned short* __restrict__ Kb,
    const unsigned short* __restrict__ Vb, unsigned short* __restrict__ Abf) {
  __shared__ unsigned short k_l[4 * 4096];  // 32 KiB
  __shared__ unsigned short v_l[4 * 4096];  // 32 KiB
  const int t = threadIdx.x;
  const int w = t >> 6;
  const int l = t & 63;
  const int n = l & 31;
  const int h = l >> 5;
  const int bid = blockIdx.x;
  const int gidx = (bid & 7) * 64 + (bid >> 3);  // XCD-contiguous bn
  const int bn = gidx >> 5;
  const int q0 = (gidx & 31) * 128 + w * 32;

  bf16x8 qf[4];
#pragma unroll
  for (int s = 0; s < 4; ++s)
    qf[s] = *(const bf16x8*)&Qb[((size_t)bn * HW_ + q0 + n) * 64 + s * 16 + h * 8];

  const int n7 = n & 7;
  const int rowKA = n * 64;
  const int rowKB = (32 + n) * 64;
  int kox[4];
#pragma unroll
  for (int s = 0; s < 4; ++s) kox[s] = ((2 * s + h) ^ n7) * 8;
  const int h4 = 4 * h;
  const int voA0 = ((0 ^ n7) * 8) + h4, voA1 = ((1 ^ n7) * 8) + h4;
  const int voB0 = ((2 ^ n7) * 8) + h4, voB1 = ((3 ^ n7) * 8) + h4;
  const int voC0 = ((4 ^ n7) * 8) + h4, voC1 = ((5 ^ n7) * 8) + h4;
  const int voD0 = ((6 ^ n7) * 8) + h4, voD1 = ((7 ^ n7) * 8) + h4;

  const int srow = 16 * w + (l >> 3);
  const int schunk = (l & 7) ^ ((l >> 3) & 7);
  const unsigned short* gKp = Kb + ((size_t)bn * HW_ + srow) * 64 + schunk * 8;
  const unsigned short* gVp = Vb + ((size_t)bn * 64 + srow) * HW_ + schunk * 8;
  unsigned short* kst = k_l + w * 1024;
  unsigned short* vst = v_l + w * 1024;

  f32x16 accO[2] = {};
  float l_r = 0.f;
  const f32x16 zero16 = {};

  ATTN_STAGE(0)
  ATTN_STAGE(1)

  for (int t4 = 0; t4 < 15; ++t4) {
    ATTN_PHASE(0, 2, "vmcnt(4)", 1)
    ATTN_PHASE(1, 3, "vmcnt(4)", 1)
    ATTN_PHASE(2, 0, "vmcnt(4)", 1)
    ATTN_PHASE(3, 1, "vmcnt(4)", 1)
  }
  ATTN_PHASE(0, 2, "vmcnt(4)", 1)
  ATTN_PHASE(1, 3, "vmcnt(4)", 1)
  ATTN_PHASE(2, 0, "vmcnt(4)", 0)
  ATTN_PHASE(3, 0, "vmcnt(0)", 0)

  // epilogue: normalize, emit bf16 cgroup layout for proj GEMM
  const int head = bn & 3;
  const int bb = bn >> 2;
  const float lsum = l_r + __shfl_xor(l_r, 32);
  const float inv = 1.0f / lsum;
  const int pcol = q0 + n;
#pragma unroll
  for (int dh = 0; dh < 2; ++dh)
#pragma unroll
    for (int k4 = 0; k4 < 4; ++k4) {
      uint2 uu;
      uu.x = cvt_pk_bf16(accO[dh][k4 * 4 + 0] * inv, accO[dh][k4 * 4 + 1] * inv);
      uu.y = cvt_pk_bf16(accO[dh][k4 * 4 + 2] * inv, accO[dh][k4 * 4 + 3] * inv);
      const int cg = head * 8 + dh * 4 + k4;
      *(uint2*)&Abf[((size_t)(bb * 32 + cg) * HW_ + pcol) * 8 + h4] = uu;
    }
}

// ---------------- SE pooling from bf16 cgroup, p-split x2 ----------------
__global__ __launch_bounds__(256) void pool_kernel(
    const unsigned short* __restrict__ Pbf, const unsigned short* __restrict__ Gbf,
    float* __restrict__ psum, float* __restrict__ pmaxH) {
  const int cg = blockIdx.x;  // 0..31
  const int b = blockIdx.y;
  const int half = blockIdx.z;
  const int t = threadIdx.x;
  const unsigned short* P = Pbf + ((size_t)(b * 32 + cg) * HW_ + half * 2048) * 8;
  const unsigned short* G = Gbf + ((size_t)(b * 32 + cg) * HW_ + half * 2048) * 8;
  float s[16], m[16];
#pragma unroll
  for (int i = 0; i < 16; ++i) { s[i] = 0.f; m[i] = -1e30f; }
  for (int p = t; p < 2048; p += 256) {
    uint4 a = *(const uint4*)&P[(size_t)p * 8];
    uint4 gg = *(const uint4*)&G[(size_t)p * 8];
    const uint32_t ua[4] = {a.x, a.y, a.z, a.w};
    const uint32_t ug[4] = {gg.x, gg.y, gg.z, gg.w};
#pragma unroll
    for (int q = 0; q < 4; ++q) {
      const float a0 = bf_lo(ua[q]), a1 = bf_hi(ua[q]);
      const float g0 = bf_lo(ug[q]), g1 = bf_hi(ug[q]);
      s[q * 2] += a0; s[q * 2 + 1] += a1;
      m[q * 2] = fmaxf(m[q * 2], a0); m[q * 2 + 1] = fmaxf(m[q * 2 + 1], a1);
      s[8 + q * 2] += g0; s[8 + q * 2 + 1] += g1;
      m[8 + q * 2] = fmaxf(m[8 + q * 2], g0); m[8 + q * 2 + 1] = fmaxf(m[8 + q * 2 + 1], g1);
    }
  }
#pragma unroll
  for (int i = 0; i < 16; ++i)
#pragma unroll
    for (int off = 1; off < 64; off <<= 1) {
      s[i] += __shfl_xor(s[i], off);
      m[i] = fmaxf(m[i], __shfl_xor(m[i], off));
    }
  __shared__ float red[4][32];
  const int wv = t >> 6;
  if ((t & 63) == 0) {
#pragma unroll
    for (int i = 0; i < 16; ++i) { red[wv][i] = s[i]; red[wv][16 + i] = m[i]; }
  }
  __syncthreads();
  if (t < 32) {
    const float v0 = red[0][t], v1 = red[1][t], v2 = red[2][t], v3 = red[3][t];
    if (t < 16) {
      const int ch = (t < 8) ? cg * 8 + t : 256 + cg * 8 + (t - 8);
      psum[half * 2048 + b * 512 + ch] = v0 + v1 + v2 + v3;
    } else {
      const int i = t - 16;
      const int ch = (i < 8) ? cg * 8 + i : 256 + cg * 8 + (i - 8);
      pmaxH[half * 2048 + b * 512 + ch] = fmaxf(fmaxf(v0, v1), fmaxf(v2, v3));
    }
  }
}

// ---------------- SE MLP (merges pool halves) ----------------
__global__ __launch_bounds__(256) void se_kernel(
    const float* __restrict__ psum, const float* __restrict__ pmaxH,
    const float* __restrict__ w1, const float* __restrict__ w2,
    float* __restrict__ wch) {
  const int b = blockIdx.x;
  const int t = threadIdx.x;
  __shared__ float za[512], zm[512], hs[64];
  za[t] = (psum[b * 512 + t] + psum[2048 + b * 512 + t]) * (1.f / 4096.f);
  za[256 + t] = (psum[b * 512 + 256 + t] + psum[2048 + b * 512 + 256 + t]) * (1.f / 4096.f);
  zm[t] = fmaxf(pmaxH[b * 512 + t], pmaxH[2048 + b * 512 + t]);
  zm[256 + t] = fmaxf(pmaxH[b * 512 + 256 + t], pmaxH[2048 + b * 512 + 256 + t]);
  __syncthreads();
  if (t < 64) {
    float ha = 0.f, hm = 0.f;
    for (int c = 0; c < 512; ++c) {
      const float w = w1[t * 512 + c];
      ha += w * za[c];
      hm += w * zm[c];
    }
    hs[t] = fmaxf(ha, 0.f) + fmaxf(hm, 0.f);
  }
  __syncthreads();
  for (int o = t; o < 512; o += 256) {
    float acc = 0.f;
#pragma unroll
    for (int hh = 0; hh < 64; ++hh) acc += hs[hh] * w2[o * 64 + hh];
    wch[b * 512 + o] = 1.f / (1.f + __expf(-acc));
  }
}

// ---------------- spatial-attention input: 4 ch-slices per block ----------------
__global__ __launch_bounds__(256) void sa_reduce_kernel(
    const unsigned short* __restrict__ Pbf, const unsigned short* __restrict__ Gbf,
    const float* __restrict__ wch, float* __restrict__ sa_in) {
  const int b = blockIdx.y;
  const int t = threadIdx.x;
  const int px = t & 63;
  const int sl = t >> 6;
  const int p = blockIdx.x * 64 + px;
  __shared__ float wl[512];
  __shared__ float sred[4][64], mred[4][64];
  wl[t] = wch[b * 512 + t];
  wl[256 + t] = wch[b * 512 + 256 + t];
  __syncthreads();
  float s = 0.f, mx = -1e30f;
#pragma unroll 4
  for (int k = 0; k < 16; ++k) {
    const int chunk = sl * 16 + k;
    const unsigned short* src = (chunk < 32)
        ? &Pbf[((size_t)(b * 32 + chunk) * HW_ + p) * 8]
        : &Gbf[((size_t)(b * 32 + (chunk - 32)) * HW_ + p) * 8];
    uint4 a = *(const uint4*)src;
    const uint32_t u[4] = {a.x, a.y, a.z, a.w};
#pragma unroll
    for (int q = 0; q < 4; ++q) {
      const float v0 = bf_lo(u[q]) * wl[chunk * 8 + q * 2];
      const float v1 = bf_hi(u[q]) * wl[chunk * 8 + q * 2 + 1];
      s += v0 + v1;
      mx = fmaxf(mx, fmaxf(v0, v1));
    }
  }
  sred[sl][px] = s;
  mred[sl][px] = mx;
  __syncthreads();
  if (sl == 0) {
    const float S = sred[0][px] + sred[1][px] + sred[2][px] + sred[3][px];
    const float M = fmaxf(fmaxf(mred[0][px], mred[1][px]), fmaxf(mred[2][px], mred[3][px]));
    sa_in[((size_t)b * 2 + 0) * HW_ + p] = S * (1.f / 512.f);
    sa_in[((size_t)b * 2 + 1) * HW_ + p] = M;
  }
}

// ---------------- 7x7 spatial conv + sigmoid -> wsp ----------------
__global__ __launch_bounds__(256) void sa_conv_kernel(
    const float* __restrict__ sa_in, const float* __restrict__ sa_w,
    float* __restrict__ wsp) {
  const int b = blockIdx.y;
  const int t = threadIdx.x;
  __shared__ float pl[2][64][64];
  __shared__ float wl[98];
  for (int e = t; e < 8192; e += 256) ((float*)pl)[e] = sa_in[(size_t)b * 8192 + e];
  if (t < 98) wl[t] = sa_w[t];
  __syncthreads();
  const int pix = blockIdx.x * 256 + t;
  const int y = pix >> 6, x = pix & 63;
  float acc = 0.f;
#pragma unroll
  for (int ic = 0; ic < 2; ++ic)
#pragma unroll
    for (int ky = 0; ky < 7; ++ky) {
      const int yy = y + ky - 3;
      if (yy < 0 || yy > 63) continue;
#pragma unroll
      for (int kx = 0; kx < 7; ++kx) {
        const int xx = x + kx - 3;
        if (xx < 0 || xx > 63) continue;
        acc += pl[ic][yy][xx] * wl[ic * 49 + ky * 7 + kx];
      }
    }
  wsp[(size_t)b * HW_ + pix] = 1.f / (1.f + __expf(-acc));
}

// ---------------- gate (split-x): catg[b][yp:66][xi:80][ic:512] bf16, halo=0 ----------------
// grid (66, 2, 4): blockIdx.y = x-half; 32KB tile -> 4 blocks/CU.
__global__ __launch_bounds__(256) void gate_kernel(
    const unsigned short* __restrict__ Pbf, const unsigned short* __restrict__ Gbf,
    const float* __restrict__ wch, const float* __restrict__ wsp,
    unsigned short* __restrict__ catg) {
  const int yp = blockIdx.x;  // 0..65
  const int xh = blockIdx.y;  // 0..1
  const int b = blockIdx.z;
  const int t = threadIdx.x;
  unsigned short* rowp = catg + ((size_t)b * 66 + yp) * 80 * 512;
  if (yp == 0 || yp == 65) {
    short8v z = {};
    for (int m = t; m < 2560; m += 256)
      *(short8v*)&rowp[((size_t)xh * 40 * 512) + m * 8] = z;
    return;
  }
  const int y = yp - 1;
  __shared__ unsigned short tile[32][512];  // [x_local][ch], chunk XOR-swizzled by (x&7)
  __shared__ float wchl[512];
  __shared__ float wspl[32];
  for (int e = t; e < 512; e += 256) wchl[e] = wch[b * 512 + e];
  if (t < 32) wspl[t] = wsp[(size_t)b * HW_ + y * 64 + xh * 32 + t];
  {  // halo zero: xh0 -> xi 0..7, xh1 -> xi 72..79
    short8v z = {};
    const int xbase = xh ? 72 : 0;
    for (int m = t; m < 512; m += 256)
      *(short8v*)&rowp[(size_t)(xbase + (m >> 6)) * 512 + (m & 63) * 8] = z;
  }
  __syncthreads();
  const int xl = t & 31;
  const int x = xh * 32 + xl;
  const int cs = t >> 5;  // 0..7
  const float wx = wspl[xl];
#pragma unroll
  for (int k = 0; k < 8; ++k) {
    const int chunk = cs * 8 + k;  // 0..63 (proj: 0..31, gray: 32..63)
    const unsigned short* src = (chunk < 32)
        ? &Pbf[((size_t)(b * 32 + chunk) * HW_ + y * 64 + x) * 8]
        : &Gbf[((size_t)(b * 32 + (chunk - 32)) * HW_ + y * 64 + x) * 8];
    uint4 a = *(const uint4*)src;
    const uint32_t u[4] = {a.x, a.y, a.z, a.w};
    uint32_t o[4];
#pragma unroll
    for (int q = 0; q < 4; ++q) {
      const float lo = bf_lo(u[q]) * wchl[chunk * 8 + q * 2] * wx;
      const float hi = bf_hi(u[q]) * wchl[chunk * 8 + q * 2 + 1] * wx;
      o[q] = cvt_pk_bf16(lo, hi);
    }
    uint4 ov = {o[0], o[1], o[2], o[3]};
    *(uint4*)&tile[xl][(chunk ^ (xl & 7)) * 8] = ov;
  }
  __syncthreads();
#pragma unroll
  for (int j = 0; j < 8; ++j) {
    const int idx = j * 256 + t;  // 0..2047
    const int xi_l = idx >> 6;    // 0..31
    const int c8 = idx & 63;
    uint4 v = *(const uint4*)&tile[xi_l][(c8 ^ (xi_l & 7)) * 8];
    *(uint4*)&rowp[(size_t)(xh * 32 + xi_l + 8) * 512 + c8 * 8] = v;
  }
}

// ---------------- fuse conv via MFMA: 32-oc tiles, 512 blocks, XCD-grouped ----------------
__global__ __launch_bounds__(256) void fuse_mfma_kernel(
    const unsigned short* __restrict__ catg, const unsigned short* __restrict__ wt,
    const float* __restrict__ bn_g, const float* __restrict__ bn_b,
    const float* __restrict__ bn_m, const float* __restrict__ bn_v,
    float* __restrict__ out) {
  __shared__ unsigned short X_l[2][6][2][80][8];  // 30 KiB
  __shared__ unsigned short W_l[2][9][2][32][8];  // 18 KiB
  __shared__ float invl[32], shl[32];
  const int t = threadIdx.x;
  const int w = t >> 6;
  const int l = t & 63;
  const int n = l & 31;
  const int g = l >> 5;
  const int i = blockIdx.x;
  const int xcd = i & 7, slot = i >> 3;
  const int ocB = slot & 7;
  const int yb = xcd + 8 * (slot >> 3);
  const int y0 = (yb & 15) * 4;
  const int o0 = ocB * 32;
  const int b = yb >> 4;

  if (t < 32) {
    const float iv = bn_g[o0 + t] * rsqrtf(bn_v[o0 + t] + 1e-5f);
    invl[t] = iv;
    shl[t] = bn_b[o0 + t] - bn_m[o0 + t] * iv;
  }

  const unsigned short* catb = catg + ((size_t)b * 66 + y0) * 80 * 512;

  auto stageX = [&](int bi, int ic0) {
    for (int wc = w; wc < 15; wc += 4) {
      const int m = wc * 64 + l;
      const int lr = m / 160;
      const int rem = m - lr * 160;
      const int half = rem / 80;
      const int xi = rem - half * 80;
      gld_lds16(catb + ((size_t)lr * 80 + xi) * 512 + ic0 + half * 8,
                &X_l[bi][0][0][0][0] + (size_t)wc * 512);
    }
  };
  auto stageW = [&](int bi, int ic0) {
    for (int wc = w; wc < 9; wc += 4) {
      const int m = wc * 64 + l;
      const int tap = m >> 6;
      const int rem = m & 63;
      const int half = rem >> 5;
      const int oc = rem & 31;
      gld_lds16(wt + ((size_t)tap * 256 + o0 + oc) * 512 + ic0 + half * 8,
                &W_l[bi][0][0][0][0] + (size_t)wc * 512);
    }
  };

  f32x16 acc[2] = {};

  stageX(0, 0);
  stageW(0, 0);
  int buf = 0;
  for (int ks = 0; ks < 32; ++ks) {
    asm volatile("s_waitcnt vmcnt(0)" ::: "memory");
    __syncthreads();
    if (ks < 31) {
      stageX(buf ^ 1, (ks + 1) * 16);
      stageW(buf ^ 1, (ks + 1) * 16);
    }
    __builtin_amdgcn_s_setprio(1);
#pragma unroll
    for (int ky = 0; ky < 3; ++ky) {
      const int lr = w + ky;
#pragma unroll
      for (int kx = 0; kx < 3; ++kx) {
        const int tap = ky * 3 + kx;
        bf16x8 a0 = *(const bf16x8*)&W_l[buf][tap][g][n][0];
        bf16x8 b0 = *(const bf16x8*)&X_l[buf][lr][g][n + kx + 7][0];
        bf16x8 b1 = *(const bf16x8*)&X_l[buf][lr][g][32 + n + kx + 7][0];
        acc[0] = __builtin_amdgcn_mfma_f32_32x32x16_bf16(a0, b0, acc[0], 0, 0, 0);
        acc[1] = __builtin_amdgcn_mfma_f32_32x32x16_bf16(a0, b1, acc[1], 0, 0, 0);
      }
    }
    __builtin_amdgcn_s_setprio(0);
    buf ^= 1;
  }

#pragma unroll
  for (int pf = 0; pf < 2; ++pf)
#pragma unroll
    for (int r = 0; r < 16; ++r) {
      const int row = (r & 3) + 8 * (r >> 2) + 4 * g;
      const float yv = acc[pf][r] * invl[row] + shl[row];
      const float ov = yv > 0.f ? yv : 0.2f * yv;
      out[((size_t)b * 256 + o0 + row) * HW_ + (size_t)(y0 + w) * 64 + pf * 32 + n] = ov;
    }
}

extern "C" void kernel_launch(void* const* d_in, const int* in_sizes, int n_in,
                              void* d_out, int out_size, void* d_ws, size_t ws_size,
                              hipStream_t stream) {
  const float* color  = (const float*)d_in[0];
  const float* gray   = (const float*)d_in[1];
  const float* Wq     = (const float*)d_in[2];
  const float* Wk     = (const float*)d_in[3];
  const float* Wv     = (const float*)d_in[4];
  const float* Wproj  = (const float*)d_in[5];
  const float* ca_w1  = (const float*)d_in[6];
  const float* ca_w2  = (const float*)d_in[7];
  const float* sa_w   = (const float*)d_in[8];
  const float* fuse_w = (const float*)d_in[9];
  const float* bn_g   = (const float*)d_in[10];
  const float* bn_b   = (const float*)d_in[11];
  const float* bn_m   = (const float*)d_in[12];
  const float* bn_v   = (const float*)d_in[13];
  float* out = (float*)d_out;

  char* ws = (char*)d_ws;
  unsigned short* Cbf = (unsigned short*)(ws);
  unsigned short* Gbf = (unsigned short*)(ws + (8u << 20));
  unsigned short* Qbf = (unsigned short*)(ws + (16u << 20));
  unsigned short* Kbf = (unsigned short*)(ws + (24u << 20));
  unsigned short* Vbf = (unsigned short*)(ws + (32u << 20));
  unsigned short* Abf = (unsigned short*)(ws);
  unsigned short* Pbf = (unsigned short*)(ws + (16u << 20));
  unsigned short* catg = (unsigned short*)(ws + (24u << 20));
  unsigned short* WqB = (unsigned short*)(ws + (45u << 20));
  unsigned short* WkB = WqB + 65536;
  unsigned short* WvB = WkB + 65536;
  unsigned short* WpB = WvB + 65536;
  unsigned short* Wt  = (unsigned short*)(ws + (45u << 20) + (1u << 19));
  float* psum  = (float*)(ws + (48u << 20));  // [2][2048]
  float* pmaxH = psum + 4096;                 // [2][2048]
  float* wch   = pmaxH + 4096;
  float* sa_in = wch + 2048;     // 32768
  float* wsp   = sa_in + 32768;  // 16384
  (void)in_sizes; (void)n_in; (void)out_size; (void)ws_size;

  const float qscale = 0.125f * 1.44269504f;

  prep_kernel<<<dim3(640), 256, 0, stream>>>(Wq, Wk, Wv, Wproj, fuse_w,
                                             WqB, WkB, WvB, WpB, Wt);
  xconv_kernel<<<dim3(2048), 256, 0, stream>>>(color, Cbf);
  xconv_kernel<<<dim3(2048), 256, 0, stream>>>(gray, Gbf);

  dim3 g_gemm(32, 4, 4);
  gemm_mfma_kernel<<<g_gemm, 256, 0, stream>>>(Cbf, WqB, Qbf, 1, qscale);
  gemm_kv_kernel<<<g_gemm, 256, 0, stream>>>(Gbf, WkB, WvB, Kbf, Vbf);
  attn_mfma_kernel<<<dim3(512), 256, 0, stream>>>(Qbf, Kbf, Vbf, Abf);
  gemm_mfma_kernel<<<g_gemm, 256, 0, stream>>>(Abf, WpB, Pbf, 3, 1.0f);

  pool_kernel<<<dim3(32, 4, 2), 256, 0, stream>>>(Pbf, Gbf, psum, pmaxH);
  se_kernel<<<dim3(4), 256, 0, stream>>>(psum, pmaxH, ca_w1, ca_w2, wch);
  sa_reduce_kernel<<<dim3(64, 4), 256, 0, stream>>>(Pbf, Gbf, wch, sa_in);
  sa_conv_kernel<<<dim3(16, 4), 256, 0, stream>>>(sa_in, sa_w, wsp);
  gate_kernel<<<dim3(66, 2, 4), 256, 0, stream>>>(Pbf, Gbf, wch, wsp, catg);
  fuse_mfma_kernel<<<dim3(512), 256, 0, stream>>>(catg, Wt, bn_g, bn_b, bn_m, bn_v, out);
}

// Round 11
// 242.737 us; speedup vs baseline: 1.0750x; 1.0420x over previous
//
#include <hip/hip_runtime.h>
#include <hip/hip_bf16.h>
#include <stdint.h>

#define HW_ 4096

typedef short bf16x8 __attribute__((ext_vector_type(8)));
typedef short short4v __attribute__((ext_vector_type(4)));
typedef short short8v __attribute__((ext_vector_type(8)));
typedef float f32x4 __attribute__((ext_vector_type(4)));
typedef float f32x16 __attribute__((ext_vector_type(16)));
typedef uint32_t u32x4 __attribute__((ext_vector_type(4)));

__device__ inline unsigned short f2bf(float x) {
  uint32_t u = __builtin_bit_cast(uint32_t, x);
  uint32_t r = ((u >> 16) & 1u) + 0x7fffu;
  return (unsigned short)((u + r) >> 16);
}
__device__ inline uint32_t cvt_pk_bf16(float lo, float hi) {
  uint32_t r;
  asm("v_cvt_pk_bf16_f32 %0, %1, %2" : "=v"(r) : "v"(lo), "v"(hi));
  return r;
}
__device__ inline float bf_lo(uint32_t u) { return __builtin_bit_cast(float, u << 16); }
__device__ inline float bf_hi(uint32_t u) { return __builtin_bit_cast(float, u & 0xffff0000u); }
__device__ inline void gld_lds16(const unsigned short* g, unsigned short* l) {
  __builtin_amdgcn_global_load_lds((const __attribute__((address_space(1))) void*)g,
                                   (__attribute__((address_space(3))) void*)l, 16, 0, 0);
}

// fused waitcnt+barrier: single asm block with memory clobber so NO memory op
// can cross the barrier. Raw s_barrier alone is NOT an IR-level memory fence.
#define WAIT_BARRIER(VMSTR)                                                  \
  asm volatile("s_waitcnt " VMSTR "\n\ts_barrier" ::: "memory");             \
  __builtin_amdgcn_sched_barrier(0);

// ---------------- prep: xconv(color,gray) + 4x wconv + wtrans, one launch ----------------
__global__ __launch_bounds__(256) void prep_kernel(
    const float* __restrict__ color, const float* __restrict__ gray,
    const float* __restrict__ Wq, const float* __restrict__ Wk,
    const float* __restrict__ Wv, const float* __restrict__ Wp,
    const float* __restrict__ fw,
    unsigned short* __restrict__ Cbf, unsigned short* __restrict__ Gbf,
    unsigned short* __restrict__ WqB, unsigned short* __restrict__ WkB,
    unsigned short* __restrict__ WvB, unsigned short* __restrict__ WpB,
    unsigned short* __restrict__ wt) {
  const int blk = blockIdx.x;
  const int t = threadIdx.x;
  if (blk < 4096) {
    // xconv: fp32 [b][c][p] -> bf16 cgroup [(b*32+cg)][p][e]
    const float* X = (blk < 2048) ? color : gray;
    unsigned short* Y = (blk < 2048) ? Cbf : Gbf;
    const int i = (blk & 2047) * 256 + t;
    const int p = i & 4095;
    const int cg = (i >> 12) & 31;
    const int b = i >> 17;
    const float* src = X + ((size_t)b * 256 + cg * 8) * HW_ + p;
    float v[8];
#pragma unroll
    for (int e = 0; e < 8; ++e) v[e] = src[(size_t)e * HW_];
    uint4 o;
    o.x = cvt_pk_bf16(v[0], v[1]);
    o.y = cvt_pk_bf16(v[2], v[3]);
    o.z = cvt_pk_bf16(v[4], v[5]);
    o.w = cvt_pk_bf16(v[6], v[7]);
    *(uint4*)&Y[((size_t)(b * 32 + cg) * HW_ + p) * 8] = o;
  } else if (blk < 4224) {
    const int bb = blk - 4096;
    const int which = bb >> 5;
    const float* W = which == 0 ? Wq : which == 1 ? Wk : which == 2 ? Wv : Wp;
    unsigned short* Y = which == 0 ? WqB : which == 1 ? WkB : which == 2 ? WvB : WpB;
    const int i = (bb & 31) * 256 + t;  // 8192
    const int o = i & 255;
    const int cg = i >> 8;
    float4 a = *(const float4*)&W[(size_t)o * 256 + cg * 8];
    float4 bq = *(const float4*)&W[(size_t)o * 256 + cg * 8 + 4];
    uint4 ov;
    ov.x = cvt_pk_bf16(a.x, a.y);
    ov.y = cvt_pk_bf16(a.z, a.w);
    ov.z = cvt_pk_bf16(bq.x, bq.y);
    ov.w = cvt_pk_bf16(bq.z, bq.w);
    *(uint4*)&Y[((size_t)cg * 256 + o) * 8] = ov;
  } else {
    const size_t i = (size_t)(blk - 4224) * 256 + t;  // 256*512
    const int oc = (int)(i >> 9);
    const int ic = (int)(i & 511);
    const float* src = fw + i * 9;
#pragma unroll
    for (int tap = 0; tap < 9; ++tap)
      wt[((size_t)tap * 256 + oc) * 512 + ic] = f2bf(src[tap]);
  }
}

// ---------------- MFMA GEMM, counted-vmcnt 4-buf pipeline ----------------
#define GSTAGE(KS, BUF)                                                       \
  gld_lds16(Xb + ((size_t)((KS) * 2 + (t >> 7)) * HW_ + p0 + (t & 127)) * 8,  \
            &X_l[BUF][0][0][0] + (size_t)t * 8);
#define GCOMP(KS)                                                             \
  {                                                                           \
    bf16x8 af = *(const bf16x8*)&W_l[(KS) * 2 + g32][wo * 32 + n][0];         \
    bf16x8 b0 = *(const bf16x8*)&X_l[(KS) & 3][g32][wp * 64 + n][0];          \
    bf16x8 b1 = *(const bf16x8*)&X_l[(KS) & 3][g32][wp * 64 + 32 + n][0];     \
    acc[0] = __builtin_amdgcn_mfma_f32_32x32x16_bf16(af, b0, acc[0], 0, 0, 0);\
    acc[1] = __builtin_amdgcn_mfma_f32_32x32x16_bf16(af, b1, acc[1], 0, 0, 0);\
  }

__global__ __launch_bounds__(256) void gemm_mfma_kernel(
    const unsigned short* __restrict__ Xbf, const unsigned short* __restrict__ Wbf,
    void* __restrict__ Yv, int mode, float oscale) {
  __shared__ unsigned short W_l[32][64][8];     // 32KB, staged once
  __shared__ unsigned short X_l[4][2][128][8];  // 16KB ring
  const int t = threadIdx.x;
  const int w = t >> 6;
  const int l = t & 63;
  const int n = l & 31;
  const int g32 = l >> 5;
  const int p0 = blockIdx.x * 128;
  const int o0 = blockIdx.y * 64;
  const int b = blockIdx.z;
  const int wo = w >> 1, wp = w & 1;
  const unsigned short* Xb = Xbf + (size_t)b * 32 * HW_ * 8;

#pragma unroll
  for (int j = 0; j < 8; ++j) {
    const int i = j * 256 + t;
    gld_lds16(Wbf + ((size_t)(i >> 6) * 256 + o0 + (i & 63)) * 8,
              &W_l[0][0][0] + (size_t)i * 8);
  }
  GSTAGE(0, 0)
  GSTAGE(1, 1)
  GSTAGE(2, 2)

  f32x16 acc[2] = {};
  for (int ks = 0; ks < 13; ++ks) {
    WAIT_BARRIER("vmcnt(2)")
    GSTAGE(ks + 3, (ks + 3) & 3)
    GCOMP(ks)
  }
  WAIT_BARRIER("vmcnt(2)")
  GCOMP(13)
  WAIT_BARRIER("vmcnt(1)")
  GCOMP(14)
  WAIT_BARRIER("vmcnt(0)")
  GCOMP(15)

  if (mode == 1) {
    unsigned short* Y = (unsigned short*)Yv;
    const size_t bh = (size_t)b * 4 + blockIdx.y;
#pragma unroll
    for (int pf = 0; pf < 2; ++pf) {
      const int p = p0 + wp * 64 + pf * 32 + n;
      unsigned short* dst = Y + (bh * HW_ + p) * 64 + wo * 32 + 4 * g32;
#pragma unroll
      for (int q = 0; q < 4; ++q) {
        uint2 uu;
        uu.x = cvt_pk_bf16(acc[pf][q * 4 + 0] * oscale, acc[pf][q * 4 + 1] * oscale);
        uu.y = cvt_pk_bf16(acc[pf][q * 4 + 2] * oscale, acc[pf][q * 4 + 3] * oscale);
        *(uint2*)&dst[8 * q] = uu;
      }
    }
  } else {  // mode 3: bf16 cgroup [(b*32+cg)][p][e]
    unsigned short* Y = (unsigned short*)Yv;
    const int cgb = (o0 + wo * 32) >> 3;
#pragma unroll
    for (int pf = 0; pf < 2; ++pf) {
      const int p = p0 + wp * 64 + pf * 32 + n;
#pragma unroll
      for (int q = 0; q < 4; ++q) {
        uint2 uu;
        uu.x = cvt_pk_bf16(acc[pf][q * 4 + 0], acc[pf][q * 4 + 1]);
        uu.y = cvt_pk_bf16(acc[pf][q * 4 + 2], acc[pf][q * 4 + 3]);
        *(uint2*)&Y[((size_t)(b * 32 + cgb + q) * HW_ + p) * 8 + 4 * g32] = uu;
      }
    }
  }
}

// ---------------- fused K+V GEMM: stages X once, two W tiles ----------------
#define GCOMP_KV(KS)                                                          \
  {                                                                           \
    bf16x8 afk = *(const bf16x8*)&W_l[0][(KS) * 2 + g32][wo * 32 + n][0];     \
    bf16x8 afv = *(const bf16x8*)&W_l[1][(KS) * 2 + g32][wo * 32 + n][0];     \
    bf16x8 b0 = *(const bf16x8*)&X_l[(KS) & 3][g32][wp * 64 + n][0];          \
    bf16x8 b1 = *(const bf16x8*)&X_l[(KS) & 3][g32][wp * 64 + 32 + n][0];     \
    accK[0] = __builtin_amdgcn_mfma_f32_32x32x16_bf16(afk, b0, accK[0], 0, 0, 0); \
    accK[1] = __builtin_amdgcn_mfma_f32_32x32x16_bf16(afk, b1, accK[1], 0, 0, 0); \
    accV[0] = __builtin_amdgcn_mfma_f32_32x32x16_bf16(afv, b0, accV[0], 0, 0, 0); \
    accV[1] = __builtin_amdgcn_mfma_f32_32x32x16_bf16(afv, b1, accV[1], 0, 0, 0); \
  }

__global__ __launch_bounds__(256) void gemm_kv_kernel(
    const unsigned short* __restrict__ Xbf, const unsigned short* __restrict__ WkB,
    const unsigned short* __restrict__ WvB, unsigned short* __restrict__ Kout,
    unsigned short* __restrict__ Vout) {
  __shared__ unsigned short W_l[2][32][64][8];  // 64KB, staged once
  __shared__ unsigned short X_l[4][2][128][8];  // 16KB ring
  const int t = threadIdx.x;
  const int w = t >> 6;
  const int l = t & 63;
  const int n = l & 31;
  const int g32 = l >> 5;
  const int p0 = blockIdx.x * 128;
  const int o0 = blockIdx.y * 64;
  const int b = blockIdx.z;
  const int wo = w >> 1, wp = w & 1;
  const unsigned short* Xb = Xbf + (size_t)b * 32 * HW_ * 8;

#pragma unroll
  for (int j = 0; j < 16; ++j) {
    const int i = j * 256 + t;          // 0..4095
    const int ii = i & 2047;
    const unsigned short* Wsrc = (i >> 11) ? WvB : WkB;
    gld_lds16(Wsrc + ((size_t)(ii >> 6) * 256 + o0 + (ii & 63)) * 8,
              &W_l[0][0][0][0] + (size_t)i * 8);
  }
  GSTAGE(0, 0)
  GSTAGE(1, 1)
  GSTAGE(2, 2)

  f32x16 accK[2] = {};
  f32x16 accV[2] = {};
  for (int ks = 0; ks < 13; ++ks) {
    WAIT_BARRIER("vmcnt(2)")
    GSTAGE(ks + 3, (ks + 3) & 3)
    GCOMP_KV(ks)
  }
  WAIT_BARRIER("vmcnt(2)")
  GCOMP_KV(13)
  WAIT_BARRIER("vmcnt(1)")
  GCOMP_KV(14)
  WAIT_BARRIER("vmcnt(0)")
  GCOMP_KV(15)

  const size_t bh = (size_t)b * 4 + blockIdx.y;
#pragma unroll
  for (int pf = 0; pf < 2; ++pf) {
    const int p = p0 + wp * 64 + pf * 32 + n;
    unsigned short* dst = Kout + (bh * HW_ + p) * 64 + wo * 32 + 4 * g32;
#pragma unroll
    for (int q = 0; q < 4; ++q) {
      uint2 uu;
      uu.x = cvt_pk_bf16(accK[pf][q * 4 + 0], accK[pf][q * 4 + 1]);
      uu.y = cvt_pk_bf16(accK[pf][q * 4 + 2], accK[pf][q * 4 + 3]);
      *(uint2*)&dst[8 * q] = uu;
    }
  }
#pragma unroll
  for (int pf = 0; pf < 2; ++pf) {
    const int p = p0 + wp * 64 + pf * 32 + n;
#pragma unroll
    for (int r = 0; r < 16; ++r) {
      const int m = (r & 3) + 8 * (r >> 2) + 4 * g32;
      Vout[((size_t)b * 256 + o0 + wo * 32 + m) * HW_ + p] = f2bf(accV[pf][r]);
    }
  }
}

// ---------------- MFMA flash attention: 8 waves/block (QB=256), 4-buf counted-vmcnt ----------------
// Whole block stages one 64x64 K tile + V tile per stage: thread t -> row t>>3,
// slot t&7, global chunk (t&7)^(row&7) (same swizzle invariant as reads).
#define ATTN_STAGE(SB)                                                       \
  {                                                                          \
    gld_lds16(gKp, kst + (SB) * 4096);                                       \
    gld_lds16(gVp, vst + (SB) * 4096);                                       \
    gKp += 4096;                                                             \
    gVp += 64;                                                               \
  }

#define ATTN_COMPUTE(BUF)                                                    \
  {                                                                          \
    f32x16 aS0 = zero16, aS1 = zero16;                                       \
    __builtin_amdgcn_s_setprio(1);                                           \
    _Pragma("unroll") for (int s = 0; s < 4; ++s) {                          \
      bf16x8 kf0 = *(const bf16x8*)&k_l[(BUF) * 4096 + rowKA + kox[s]];      \
      bf16x8 kf1 = *(const bf16x8*)&k_l[(BUF) * 4096 + rowKB + kox[s]];      \
      aS0 = __builtin_amdgcn_mfma_f32_32x32x16_bf16(kf0, qf[s], aS0, 0, 0, 0); \
      aS1 = __builtin_amdgcn_mfma_f32_32x32x16_bf16(kf1, qf[s], aS1, 0, 0, 0); \
    }                                                                        \
    __builtin_amdgcn_s_setprio(0);                                           \
    float ex0[16], ex1[16];                                                  \
    _Pragma("unroll") for (int r = 0; r < 16; ++r) {                         \
      ex0[r] = __builtin_amdgcn_exp2f(aS0[r]);                               \
      ex1[r] = __builtin_amdgcn_exp2f(aS1[r]);                               \
    }                                                                        \
    float rsp0 = 0.f, rsp1 = 0.f, rsp2 = 0.f, rsp3 = 0.f;                    \
    _Pragma("unroll") for (int r = 0; r < 16; r += 4) {                      \
      rsp0 += ex0[r + 0] + ex1[r + 0];                                       \
      rsp1 += ex0[r + 1] + ex1[r + 1];                                       \
      rsp2 += ex0[r + 2] + ex1[r + 2];                                       \
      rsp3 += ex0[r + 3] + ex1[r + 3];                                       \
    }                                                                        \
    l_r += (rsp0 + rsp1) + (rsp2 + rsp3);                                    \
    union { u32x4 u4; bf16x8 v8; } pA, pB, pC, pD;                           \
    pA.u4 = (u32x4){cvt_pk_bf16(ex0[0], ex0[1]), cvt_pk_bf16(ex0[2], ex0[3]),    \
                    cvt_pk_bf16(ex0[4], ex0[5]), cvt_pk_bf16(ex0[6], ex0[7])};   \
    pB.u4 = (u32x4){cvt_pk_bf16(ex0[8], ex0[9]), cvt_pk_bf16(ex0[10], ex0[11]),  \
                    cvt_pk_bf16(ex0[12], ex0[13]), cvt_pk_bf16(ex0[14], ex0[15])};\
    pC.u4 = (u32x4){cvt_pk_bf16(ex1[0], ex1[1]), cvt_pk_bf16(ex1[2], ex1[3]),    \
                    cvt_pk_bf16(ex1[4], ex1[5]), cvt_pk_bf16(ex1[6], ex1[7])};   \
    pD.u4 = (u32x4){cvt_pk_bf16(ex1[8], ex1[9]), cvt_pk_bf16(ex1[10], ex1[11]),  \
                    cvt_pk_bf16(ex1[12], ex1[13]), cvt_pk_bf16(ex1[14], ex1[15])};\
    __builtin_amdgcn_s_setprio(1);                                           \
    _Pragma("unroll") for (int dh = 0; dh < 2; ++dh) {                       \
      const int rw = (BUF) * 4096 + (dh * 32 + n) * 64;                      \
      union { short4v h2[2]; bf16x8 v8; } v0, v1, v2, v3;                    \
      v0.h2[0] = *(const short4v*)&v_l[rw + voA0];                           \
      v0.h2[1] = *(const short4v*)&v_l[rw + voA1];                           \
      v1.h2[0] = *(const short4v*)&v_l[rw + voB0];                           \
      v1.h2[1] = *(const short4v*)&v_l[rw + voB1];                           \
      v2.h2[0] = *(const short4v*)&v_l[rw + voC0];                           \
      v2.h2[1] = *(const short4v*)&v_l[rw + voC1];                           \
      v3.h2[0] = *(const short4v*)&v_l[rw + voD0];                           \
      v3.h2[1] = *(const short4v*)&v_l[rw + voD1];                           \
      f32x16 ac = accO[dh];                                                  \
      ac = __builtin_amdgcn_mfma_f32_32x32x16_bf16(v0.v8, pA.v8, ac, 0, 0, 0); \
      ac = __builtin_amdgcn_mfma_f32_32x32x16_bf16(v1.v8, pB.v8, ac, 0, 0, 0); \
      ac = __builtin_amdgcn_mfma_f32_32x32x16_bf16(v2.v8, pC.v8, ac, 0, 0, 0); \
      ac = __builtin_amdgcn_mfma_f32_32x32x16_bf16(v3.v8, pD.v8, ac, 0, 0, 0); \
      accO[dh] = ac;                                                         \
    }                                                                        \
    __builtin_amdgcn_s_setprio(0);                                           \
  }

#define ATTN_PHASE(B, SB, VMSTR, DOST)                                       \
  WAIT_BARRIER(VMSTR)                                                        \
  if (DOST) { ATTN_STAGE(SB) }                                               \
  ATTN_COMPUTE(B)

__global__ __launch_bounds__(512) void attn_mfma_kernel(
    const unsigned short* __restrict__ Qb, const unsigned short* __restrict__ Kb,
    const unsigned short* __restrict__ Vb, unsigned short* __restrict__ Abf) {
  __shared__ unsigned short k_l[4 * 4096];  // 32 KiB
  __shared__ unsigned short v_l[4 * 4096];  // 32 KiB
  const int t = threadIdx.x;
  const int w = t >> 6;
  const int l = t & 63;
  const int n = l & 31;
  const int h = l >> 5;
  const int bid = blockIdx.x;
  // grid 256 = 16 bn x 16 q-tiles; XCD-contiguous: 2 bn per XCD (K/V L2-resident)
  const int gidx = (bid & 7) * 32 + (bid >> 3);
  const int bn = gidx >> 4;
  const int q0 = (gidx & 15) * 256 + w * 32;

  bf16x8 qf[4];
#pragma unroll
  for (int s = 0; s < 4; ++s)
    qf[s] = *(const bf16x8*)&Qb[((size_t)bn * HW_ + q0 + n) * 64 + s * 16 + h * 8];

  const int n7 = n & 7;
  const int rowKA = n * 64;
  const int rowKB = (32 + n) * 64;
  int kox[4];
#pragma unroll
  for (int s = 0; s < 4; ++s) kox[s] = ((2 * s + h) ^ n7) * 8;
  const int h4 = 4 * h;
  const int voA0 = ((0 ^ n7) * 8) + h4, voA1 = ((1 ^ n7) * 8) + h4;
  const int voB0 = ((2 ^ n7) * 8) + h4, voB1 = ((3 ^ n7) * 8) + h4;
  const int voC0 = ((4 ^ n7) * 8) + h4, voC1 = ((5 ^ n7) * 8) + h4;
  const int voD0 = ((6 ^ n7) * 8) + h4, voD1 = ((7 ^ n7) * 8) + h4;

  // staging: thread t -> row t>>3, slot t&7, global chunk (t&7)^(row&7)
  const int srow = t >> 3;
  const int schunk = (t & 7) ^ (srow & 7);
  const unsigned short* gKp = Kb + ((size_t)bn * HW_ + srow) * 64 + schunk * 8;
  const unsigned short* gVp = Vb + ((size_t)bn * 64 + srow) * HW_ + schunk * 8;
  unsigned short* kst = k_l + w * 512;  // wave-uniform base; lane offset = l*16B
  unsigned short* vst = v_l + w * 512;

  f32x16 accO[2] = {};
  float l_r = 0.f;
  const f32x16 zero16 = {};

  ATTN_STAGE(0)
  ATTN_STAGE(1)

  for (int t4 = 0; t4 < 15; ++t4) {
    ATTN_PHASE(0, 2, "vmcnt(2)", 1)
    ATTN_PHASE(1, 3, "vmcnt(2)", 1)
    ATTN_PHASE(2, 0, "vmcnt(2)", 1)
    ATTN_PHASE(3, 1, "vmcnt(2)", 1)
  }
  ATTN_PHASE(0, 2, "vmcnt(2)", 1)
  ATTN_PHASE(1, 3, "vmcnt(2)", 1)
  ATTN_PHASE(2, 0, "vmcnt(2)", 0)
  ATTN_PHASE(3, 0, "vmcnt(0)", 0)

  // epilogue: normalize, emit bf16 cgroup layout for proj GEMM
  const int head = bn & 3;
  const int bb = bn >> 2;
  const float lsum = l_r + __shfl_xor(l_r, 32);
  const float inv = 1.0f / lsum;
  const int pcol = q0 + n;
#pragma unroll
  for (int dh = 0; dh < 2; ++dh)
#pragma unroll
    for (int k4 = 0; k4 < 4; ++k4) {
      uint2 uu;
      uu.x = cvt_pk_bf16(accO[dh][k4 * 4 + 0] * inv, accO[dh][k4 * 4 + 1] * inv);
      uu.y = cvt_pk_bf16(accO[dh][k4 * 4 + 2] * inv, accO[dh][k4 * 4 + 3] * inv);
      const int cg = head * 8 + dh * 4 + k4;
      *(uint2*)&Abf[((size_t)(bb * 32 + cg) * HW_ + pcol) * 8 + h4] = uu;
    }
}

// ---------------- SE pooling from bf16 cgroup, p-split x2 ----------------
__global__ __launch_bounds__(256) void pool_kernel(
    const unsigned short* __restrict__ Pbf, const unsigned short* __restrict__ Gbf,
    float* __restrict__ psum, float* __restrict__ pmaxH) {
  const int cg = blockIdx.x;  // 0..31
  const int b = blockIdx.y;
  const int half = blockIdx.z;
  const int t = threadIdx.x;
  const unsigned short* P = Pbf + ((size_t)(b * 32 + cg) * HW_ + half * 2048) * 8;
  const unsigned short* G = Gbf + ((size_t)(b * 32 + cg) * HW_ + half * 2048) * 8;
  float s[16], m[16];
#pragma unroll
  for (int i = 0; i < 16; ++i) { s[i] = 0.f; m[i] = -1e30f; }
  for (int p = t; p < 2048; p += 256) {
    uint4 a = *(const uint4*)&P[(size_t)p * 8];
    uint4 gg = *(const uint4*)&G[(size_t)p * 8];
    const uint32_t ua[4] = {a.x, a.y, a.z, a.w};
    const uint32_t ug[4] = {gg.x, gg.y, gg.z, gg.w};
#pragma unroll
    for (int q = 0; q < 4; ++q) {
      const float a0 = bf_lo(ua[q]), a1 = bf_hi(ua[q]);
      const float g0 = bf_lo(ug[q]), g1 = bf_hi(ug[q]);
      s[q * 2] += a0; s[q * 2 + 1] += a1;
      m[q * 2] = fmaxf(m[q * 2], a0); m[q * 2 + 1] = fmaxf(m[q * 2 + 1], a1);
      s[8 + q * 2] += g0; s[8 + q * 2 + 1] += g1;
      m[8 + q * 2] = fmaxf(m[8 + q * 2], g0); m[8 + q * 2 + 1] = fmaxf(m[8 + q * 2 + 1], g1);
    }
  }
#pragma unroll
  for (int i = 0; i < 16; ++i)
#pragma unroll
    for (int off = 1; off < 64; off <<= 1) {
      s[i] += __shfl_xor(s[i], off);
      m[i] = fmaxf(m[i], __shfl_xor(m[i], off));
    }
  __shared__ float red[4][32];
  const int wv = t >> 6;
  if ((t & 63) == 0) {
#pragma unroll
    for (int i = 0; i < 16; ++i) { red[wv][i] = s[i]; red[wv][16 + i] = m[i]; }
  }
  __syncthreads();
  if (t < 32) {
    const float v0 = red[0][t], v1 = red[1][t], v2 = red[2][t], v3 = red[3][t];
    if (t < 16) {
      const int ch = (t < 8) ? cg * 8 + t : 256 + cg * 8 + (t - 8);
      psum[half * 2048 + b * 512 + ch] = v0 + v1 + v2 + v3;
    } else {
      const int i = t - 16;
      const int ch = (i < 8) ? cg * 8 + i : 256 + cg * 8 + (i - 8);
      pmaxH[half * 2048 + b * 512 + ch] = fmaxf(fmaxf(v0, v1), fmaxf(v2, v3));
    }
  }
}

// ---------------- SE MLP (merges pool halves) ----------------
__global__ __launch_bounds__(256) void se_kernel(
    const float* __restrict__ psum, const float* __restrict__ pmaxH,
    const float* __restrict__ w1, const float* __restrict__ w2,
    float* __restrict__ wch) {
  const int b = blockIdx.x;
  const int t = threadIdx.x;
  __shared__ float za[512], zm[512], hs[64];
  za[t] = (psum[b * 512 + t] + psum[2048 + b * 512 + t]) * (1.f / 4096.f);
  za[256 + t] = (psum[b * 512 + 256 + t] + psum[2048 + b * 512 + 256 + t]) * (1.f / 4096.f);
  zm[t] = fmaxf(pmaxH[b * 512 + t], pmaxH[2048 + b * 512 + t]);
  zm[256 + t] = fmaxf(pmaxH[b * 512 + 256 + t], pmaxH[2048 + b * 512 + 256 + t]);
  __syncthreads();
  if (t < 64) {
    float ha = 0.f, hm = 0.f;
    for (int c = 0; c < 512; ++c) {
      const float w = w1[t * 512 + c];
      ha += w * za[c];
      hm += w * zm[c];
    }
    hs[t] = fmaxf(ha, 0.f) + fmaxf(hm, 0.f);
  }
  __syncthreads();
  for (int o = t; o < 512; o += 256) {
    float acc = 0.f;
#pragma unroll
    for (int hh = 0; hh < 64; ++hh) acc += hs[hh] * w2[o * 64 + hh];
    wch[b * 512 + o] = 1.f / (1.f + __expf(-acc));
  }
}

// ---------------- spatial-attention input: 4 ch-slices per block ----------------
__global__ __launch_bounds__(256) void sa_reduce_kernel(
    const unsigned short* __restrict__ Pbf, const unsigned short* __restrict__ Gbf,
    const float* __restrict__ wch, float* __restrict__ sa_in) {
  const int b = blockIdx.y;
  const int t = threadIdx.x;
  const int px = t & 63;
  const int sl = t >> 6;
  const int p = blockIdx.x * 64 + px;
  __shared__ float wl[512];
  __shared__ float sred[4][64], mred[4][64];
  wl[t] = wch[b * 512 + t];
  wl[256 + t] = wch[b * 512 + 256 + t];
  __syncthreads();
  float s = 0.f, mx = -1e30f;
#pragma unroll 4
  for (int k = 0; k < 16; ++k) {
    const int chunk = sl * 16 + k;
    const unsigned short* src = (chunk < 32)
        ? &Pbf[((size_t)(b * 32 + chunk) * HW_ + p) * 8]
        : &Gbf[((size_t)(b * 32 + (chunk - 32)) * HW_ + p) * 8];
    uint4 a = *(const uint4*)src;
    const uint32_t u[4] = {a.x, a.y, a.z, a.w};
#pragma unroll
    for (int q = 0; q < 4; ++q) {
      const float v0 = bf_lo(u[q]) * wl[chunk * 8 + q * 2];
      const float v1 = bf_hi(u[q]) * wl[chunk * 8 + q * 2 + 1];
      s += v0 + v1;
      mx = fmaxf(mx, fmaxf(v0, v1));
    }
  }
  sred[sl][px] = s;
  mred[sl][px] = mx;
  __syncthreads();
  if (sl == 0) {
    const float S = sred[0][px] + sred[1][px] + sred[2][px] + sred[3][px];
    const float M = fmaxf(fmaxf(mred[0][px], mred[1][px]), fmaxf(mred[2][px], mred[3][px]));
    sa_in[((size_t)b * 2 + 0) * HW_ + p] = S * (1.f / 512.f);
    sa_in[((size_t)b * 2 + 1) * HW_ + p] = M;
  }
}

// ---------------- 7x7 spatial conv + sigmoid -> wsp ----------------
__global__ __launch_bounds__(256) void sa_conv_kernel(
    const float* __restrict__ sa_in, const float* __restrict__ sa_w,
    float* __restrict__ wsp) {
  const int b = blockIdx.y;
  const int t = threadIdx.x;
  __shared__ float pl[2][64][64];
  __shared__ float wl[98];
  for (int e = t; e < 8192; e += 256) ((float*)pl)[e] = sa_in[(size_t)b * 8192 + e];
  if (t < 98) wl[t] = sa_w[t];
  __syncthreads();
  const int pix = blockIdx.x * 256 + t;
  const int y = pix >> 6, x = pix & 63;
  float acc = 0.f;
#pragma unroll
  for (int ic = 0; ic < 2; ++ic)
#pragma unroll
    for (int ky = 0; ky < 7; ++ky) {
      const int yy = y + ky - 3;
      if (yy < 0 || yy > 63) continue;
#pragma unroll
      for (int kx = 0; kx < 7; ++kx) {
        const int xx = x + kx - 3;
        if (xx < 0 || xx > 63) continue;
        acc += pl[ic][yy][xx] * wl[ic * 49 + ky * 7 + kx];
      }
    }
  wsp[(size_t)b * HW_ + pix] = 1.f / (1.f + __expf(-acc));
}

// ---------------- gate (split-x): catg[b][yp:66][xi:80][ic:512] bf16, halo=0 ----------------
__global__ __launch_bounds__(256) void gate_kernel(
    const unsigned short* __restrict__ Pbf, const unsigned short* __restrict__ Gbf,
    const float* __restrict__ wch, const float* __restrict__ wsp,
    unsigned short* __restrict__ catg) {
  const int yp = blockIdx.x;  // 0..65
  const int xh = blockIdx.y;  // 0..1
  const int b = blockIdx.z;
  const int t = threadIdx.x;
  unsigned short* rowp = catg + ((size_t)b * 66 + yp) * 80 * 512;
  if (yp == 0 || yp == 65) {
    short8v z = {};
    for (int m = t; m < 2560; m += 256)
      *(short8v*)&rowp[((size_t)xh * 40 * 512) + m * 8] = z;
    return;
  }
  const int y = yp - 1;
  __shared__ unsigned short tile[32][512];
  __shared__ float wchl[512];
  __shared__ float wspl[32];
  for (int e = t; e < 512; e += 256) wchl[e] = wch[b * 512 + e];
  if (t < 32) wspl[t] = wsp[(size_t)b * HW_ + y * 64 + xh * 32 + t];
  {
    short8v z = {};
    const int xbase = xh ? 72 : 0;
    for (int m = t; m < 512; m += 256)
      *(short8v*)&rowp[(size_t)(xbase + (m >> 6)) * 512 + (m & 63) * 8] = z;
  }
  __syncthreads();
  const int xl = t & 31;
  const int x = xh * 32 + xl;
  const int cs = t >> 5;
  const float wx = wspl[xl];
#pragma unroll
  for (int k = 0; k < 8; ++k) {
    const int chunk = cs * 8 + k;
    const unsigned short* src = (chunk < 32)
        ? &Pbf[((size_t)(b * 32 + chunk) * HW_ + y * 64 + x) * 8]
        : &Gbf[((size_t)(b * 32 + (chunk - 32)) * HW_ + y * 64 + x) * 8];
    uint4 a = *(const uint4*)src;
    const uint32_t u[4] = {a.x, a.y, a.z, a.w};
    uint32_t o[4];
#pragma unroll
    for (int q = 0; q < 4; ++q) {
      const float lo = bf_lo(u[q]) * wchl[chunk * 8 + q * 2] * wx;
      const float hi = bf_hi(u[q]) * wchl[chunk * 8 + q * 2 + 1] * wx;
      o[q] = cvt_pk_bf16(lo, hi);
    }
    uint4 ov = {o[0], o[1], o[2], o[3]};
    *(uint4*)&tile[xl][(chunk ^ (xl & 7)) * 8] = ov;
  }
  __syncthreads();
#pragma unroll
  for (int j = 0; j < 8; ++j) {
    const int idx = j * 256 + t;
    const int xi_l = idx >> 6;
    const int c8 = idx & 63;
    uint4 v = *(const uint4*)&tile[xi_l][(c8 ^ (xi_l & 7)) * 8];
    *(uint4*)&rowp[(size_t)(xh * 32 + xi_l + 8) * 512 + c8 * 8] = v;
  }
}

// ---------------- fuse conv via MFMA: 3-buf counted-vmcnt ring ----------------
// X_l 3x15KB + W_l 3x9KB = 72KB -> 2 blocks/CU. 7 uniform loads/wave/stage, vmcnt(7).
__global__ __launch_bounds__(256) void fuse_mfma_kernel(
    const unsigned short* __restrict__ catg, const unsigned short* __restrict__ wt,
    const float* __restrict__ bn_g, const float* __restrict__ bn_b,
    const float* __restrict__ bn_m, const float* __restrict__ bn_v,
    float* __restrict__ out) {
  __shared__ unsigned short X_l[3][6][2][80][8];  // 45 KiB
  __shared__ unsigned short W_l[3][9][2][32][8];  // 27 KiB
  __shared__ float invl[32], shl[32];
  const int t = threadIdx.x;
  const int w = t >> 6;
  const int l = t & 63;
  const int n = l & 31;
  const int g = l >> 5;
  const int i = blockIdx.x;
  const int xcd = i & 7, slot = i >> 3;
  const int ocB = slot & 7;
  const int yb = xcd + 8 * (slot >> 3);
  const int y0 = (yb & 15) * 4;
  const int o0 = ocB * 32;
  const int b = yb >> 4;

  if (t < 32) {
    const float iv = bn_g[o0 + t] * rsqrtf(bn_v[o0 + t] + 1e-5f);
    invl[t] = iv;
    shl[t] = bn_b[o0 + t] - bn_m[o0 + t] * iv;
  }

  const unsigned short* catb = catg + ((size_t)b * 66 + y0) * 80 * 512;

  // 7 loads per wave per stage (padded with duplicate chunks for uniformity)
  auto stage = [&](int bi, int ic0) {
    for (int wc = w; wc < 16; wc += 4) {  // X: chunks 0..14 (+pad 15->14)
      const int wcc = wc > 14 ? 14 : wc;
      const int m = wcc * 64 + l;
      const int lr = m / 160;
      const int rem = m - lr * 160;
      const int half = rem / 80;
      const int xi = rem - half * 80;
      gld_lds16(catb + ((size_t)lr * 80 + xi) * 512 + ic0 + half * 8,
                &X_l[bi][0][0][0][0] + (size_t)wcc * 512);
    }
    for (int wc = w; wc < 12; wc += 4) {  // W: chunks 0..8 (+pad 9..11->8)
      const int wcc = wc > 8 ? 8 : wc;
      const int m = wcc * 64 + l;
      const int tap = m >> 6;
      const int rem = m & 63;
      const int half = rem >> 5;
      const int oc = rem & 31;
      gld_lds16(wt + ((size_t)tap * 256 + o0 + oc) * 512 + ic0 + half * 8,
                &W_l[bi][0][0][0][0] + (size_t)wcc * 512);
    }
  };

#define FUSE_COMP(BI)                                                        \
  {                                                                          \
    __builtin_amdgcn_s_setprio(1);                                           \
    _Pragma("unroll") for (int ky = 0; ky < 3; ++ky) {                       \
      const int lr = w + ky;                                                 \
      _Pragma("unroll") for (int kx = 0; kx < 3; ++kx) {                     \
        const int tap = ky * 3 + kx;                                         \
        bf16x8 a0 = *(const bf16x8*)&W_l[BI][tap][g][n][0];                  \
        bf16x8 b0 = *(const bf16x8*)&X_l[BI][lr][g][n + kx + 7][0];          \
        bf16x8 b1 = *(const bf16x8*)&X_l[BI][lr][g][32 + n + kx + 7][0];     \
        acc[0] = __builtin_amdgcn_mfma_f32_32x32x16_bf16(a0, b0, acc[0], 0, 0, 0); \
        acc[1] = __builtin_amdgcn_mfma_f32_32x32x16_bf16(a0, b1, acc[1], 0, 0, 0); \
      }                                                                      \
    }                                                                        \
    __builtin_amdgcn_s_setprio(0);                                           \
  }

  f32x16 acc[2] = {};
  stage(0, 0);
  stage(1, 16);
  for (int kb = 0; kb < 10; ++kb) {
    const int ks = kb * 3;
    WAIT_BARRIER("vmcnt(7)")
    stage(2, (ks + 2) * 16);
    FUSE_COMP(0)
    WAIT_BARRIER("vmcnt(7)")
    stage(0, (ks + 3) * 16);
    FUSE_COMP(1)
    WAIT_BARRIER("vmcnt(7)")
    stage(1, (ks + 4) * 16);
    FUSE_COMP(2)
  }
  WAIT_BARRIER("vmcnt(7)")
  FUSE_COMP(0)
  WAIT_BARRIER("vmcnt(0)")
  FUSE_COMP(1)

#pragma unroll
  for (int pf = 0; pf < 2; ++pf)
#pragma unroll
    for (int r = 0; r < 16; ++r) {
      const int row = (r & 3) + 8 * (r >> 2) + 4 * g;
      const float yv = acc[pf][r] * invl[row] + shl[row];
      const float ov = yv > 0.f ? yv : 0.2f * yv;
      out[((size_t)b * 256 + o0 + row) * HW_ + (size_t)(y0 + w) * 64 + pf * 32 + n] = ov;
    }
}

extern "C" void kernel_launch(void* const* d_in, const int* in_sizes, int n_in,
                              void* d_out, int out_size, void* d_ws, size_t ws_size,
                              hipStream_t stream) {
  const float* color  = (const float*)d_in[0];
  const float* gray   = (const float*)d_in[1];
  const float* Wq     = (const float*)d_in[2];
  const float* Wk     = (const float*)d_in[3];
  const float* Wv     = (const float*)d_in[4];
  const float* Wproj  = (const float*)d_in[5];
  const float* ca_w1  = (const float*)d_in[6];
  const float* ca_w2  = (const float*)d_in[7];
  const float* sa_w   = (const float*)d_in[8];
  const float* fuse_w = (const float*)d_in[9];
  const float* bn_g   = (const float*)d_in[10];
  const float* bn_b   = (const float*)d_in[11];
  const float* bn_m   = (const float*)d_in[12];
  const float* bn_v   = (const float*)d_in[13];
  float* out = (float*)d_out;

  char* ws = (char*)d_ws;
  unsigned short* Cbf = (unsigned short*)(ws);
  unsigned short* Gbf = (unsigned short*)(ws + (8u << 20));
  unsigned short* Qbf = (unsigned short*)(ws + (16u << 20));
  unsigned short* Kbf = (unsigned short*)(ws + (24u << 20));
  unsigned short* Vbf = (unsigned short*)(ws + (32u << 20));
  unsigned short* Abf = (unsigned short*)(ws);
  unsigned short* Pbf = (unsigned short*)(ws + (16u << 20));
  unsigned short* catg = (unsigned short*)(ws + (24u << 20));
  unsigned short* WqB = (unsigned short*)(ws + (45u << 20));
  unsigned short* WkB = WqB + 65536;
  unsigned short* WvB = WkB + 65536;
  unsigned short* WpB = WvB + 65536;
  unsigned short* Wt  = (unsigned short*)(ws + (45u << 20) + (1u << 19));
  float* psum  = (float*)(ws + (48u << 20));  // [2][2048]
  float* pmaxH = psum + 4096;                 // [2][2048]
  float* wch   = pmaxH + 4096;
  float* sa_in = wch + 2048;     // 32768
  float* wsp   = sa_in + 32768;  // 16384
  (void)in_sizes; (void)n_in; (void)out_size; (void)ws_size;

  const float qscale = 0.125f * 1.44269504f;

  prep_kernel<<<dim3(4736), 256, 0, stream>>>(color, gray, Wq, Wk, Wv, Wproj, fuse_w,
                                              Cbf, Gbf, WqB, WkB, WvB, WpB, Wt);

  dim3 g_gemm(32, 4, 4);
  gemm_mfma_kernel<<<g_gemm, 256, 0, stream>>>(Cbf, WqB, Qbf, 1, qscale);
  gemm_kv_kernel<<<g_gemm, 256, 0, stream>>>(Gbf, WkB, WvB, Kbf, Vbf);
  attn_mfma_kernel<<<dim3(256), 512, 0, stream>>>(Qbf, Kbf, Vbf, Abf);
  gemm_mfma_kernel<<<g_gemm, 256, 0, stream>>>(Abf, WpB, Pbf, 3, 1.0f);

  pool_kernel<<<dim3(32, 4, 2), 256, 0, stream>>>(Pbf, Gbf, psum, pmaxH);
  se_kernel<<<dim3(4), 256, 0, stream>>>(psum, pmaxH, ca_w1, ca_w2, wch);
  sa_reduce_kernel<<<dim3(64, 4), 256, 0, stream>>>(Pbf, Gbf, wch, sa_in);
  sa_conv_kernel<<<dim3(16, 4), 256, 0, stream>>>(sa_in, sa_w, wsp);
  gate_kernel<<<dim3(66, 2, 4), 256, 0, stream>>>(Pbf, Gbf, wch, wsp, catg);
  fuse_mfma_kernel<<<dim3(512), 256, 0, stream>>>(catg, Wt, bn_g, bn_b, bn_m, bn_v, out);
}